// Round 1
// baseline (710.447 us; speedup 1.0000x reference)
//
#include <hip/hip_runtime.h>

#define TOK 8192       // B*N rows
#define DMODEL 512
#define SEQ 1024
#define NH 8
#define DH 64

// ---------------- LayerNorm: one wave per row ----------------
__global__ __launch_bounds__(64) void ln_kernel(
    const float* __restrict__ x, const float* __restrict__ gamma,
    const float* __restrict__ beta, float* __restrict__ xn) {
  const int row = blockIdx.x;
  const int t = threadIdx.x;
  const float* xr = x + (size_t)row * DMODEL;
  const float4 a = *(const float4*)(xr + t * 4);
  const float4 b = *(const float4*)(xr + 256 + t * 4);
  float s  = a.x + a.y + a.z + a.w + b.x + b.y + b.z + b.w;
  float ss = a.x*a.x + a.y*a.y + a.z*a.z + a.w*a.w
           + b.x*b.x + b.y*b.y + b.z*b.z + b.w*b.w;
  #pragma unroll
  for (int m = 1; m < 64; m <<= 1) {
    s  += __shfl_xor(s, m);
    ss += __shfl_xor(ss, m);
  }
  const float mean = s * (1.0f / DMODEL);
  const float var  = ss * (1.0f / DMODEL) - mean * mean;
  const float inv  = rsqrtf(var + 1e-5f);
  const float4 g0  = *(const float4*)(gamma + t * 4);
  const float4 g1  = *(const float4*)(gamma + 256 + t * 4);
  const float4 be0 = *(const float4*)(beta + t * 4);
  const float4 be1 = *(const float4*)(beta + 256 + t * 4);
  float4 o0, o1;
  o0.x = (a.x - mean) * inv * g0.x + be0.x;
  o0.y = (a.y - mean) * inv * g0.y + be0.y;
  o0.z = (a.z - mean) * inv * g0.z + be0.z;
  o0.w = (a.w - mean) * inv * g0.w + be0.w;
  o1.x = (b.x - mean) * inv * g1.x + be1.x;
  o1.y = (b.y - mean) * inv * g1.y + be1.y;
  o1.z = (b.z - mean) * inv * g1.z + be1.z;
  o1.w = (b.w - mean) * inv * g1.w + be1.w;
  float* outr = xn + (size_t)row * DMODEL;
  *(float4*)(outr + t * 4) = o0;
  *(float4*)(outr + 256 + t * 4) = o1;
}

// ---------------- fp32 SGEMM: C[M,N] = A[M,K] * B[K,N] ----------------
#define BM 128
#define BN 128
#define BK 8

__global__ __launch_bounds__(256) void sgemm_kernel(
    const float* __restrict__ A, const float* __restrict__ B,
    float* __restrict__ C, int M, int N, int K) {
  __shared__ float As[BK][BM];   // A tile stored transposed: As[k][m]
  __shared__ float Bs[BK][BN];
  const int bn = blockIdx.x, bm = blockIdx.y;
  const int tid = threadIdx.x;
  const int ry = tid >> 4, rx = tid & 15;      // 16x16 threads, 8x8 micro-tile
  const int am = tid >> 1, ak = (tid & 1) * 4; // A staging coords
  const int bkr = tid >> 5, bnc = (tid & 31) * 4;
  const float* Ap = A + (size_t)(bm * BM + am) * K + ak;
  const float* Bp = B + (size_t)bkr * N + bn * BN + bnc;
  float acc[8][8] = {};
  for (int k0 = 0; k0 < K; k0 += BK) {
    const float4 av = *(const float4*)(Ap + k0);
    const float4 bv = *(const float4*)(Bp + (size_t)k0 * N);
    As[ak + 0][am] = av.x;
    As[ak + 1][am] = av.y;
    As[ak + 2][am] = av.z;
    As[ak + 3][am] = av.w;
    *(float4*)&Bs[bkr][bnc] = bv;
    __syncthreads();
    #pragma unroll
    for (int kk = 0; kk < BK; kk++) {
      float a[8], b[8];
      *(float4*)(a)     = *(const float4*)&As[kk][ry * 8];
      *(float4*)(a + 4) = *(const float4*)&As[kk][ry * 8 + 4];
      *(float4*)(b)     = *(const float4*)&Bs[kk][rx * 8];
      *(float4*)(b + 4) = *(const float4*)&Bs[kk][rx * 8 + 4];
      #pragma unroll
      for (int i = 0; i < 8; i++)
        #pragma unroll
        for (int j = 0; j < 8; j++)
          acc[i][j] = fmaf(a[i], b[j], acc[i][j]);
    }
    __syncthreads();
  }
  const int crow0 = bm * BM + ry * 8;
  const int ccol0 = bn * BN + rx * 8;
  #pragma unroll
  for (int i = 0; i < 8; i++) {
    float* cp = C + (size_t)(crow0 + i) * N + ccol0;
    *(float4*)cp       = make_float4(acc[i][0], acc[i][1], acc[i][2], acc[i][3]);
    *(float4*)(cp + 4) = make_float4(acc[i][4], acc[i][5], acc[i][6], acc[i][7]);
  }
}

// ---------------- flash attention, fp32, 64x64 tiles ----------------
// qkb: [TOK,1024]  cols [h*64+d] = q, cols [512+h*64+d] = k
// vbuf: [TOK,512]  cols [h*64+d] = v
// ao:  [TOK,512]   output in b n (h d) layout
__global__ __launch_bounds__(256) void flash_kernel(
    const float* __restrict__ qkb, const float* __restrict__ vbuf,
    float* __restrict__ ao) {
  __shared__ float Qs[64][64];
  __shared__ float Ks[64][64];   // quad-XOR-swizzled along d
  __shared__ float Vs[64][64];
  __shared__ float Ps[64][64];
  const int qt = blockIdx.x;     // 0..15 q-tile
  const int bh = blockIdx.y;     // 0..63
  const int b = bh >> 3, h = bh & 7;
  const int tid = threadIdx.x;
  const int ty = tid >> 4, tx = tid & 15;
  const int lr = tid >> 4;
  const int lc = (tid & 15) * 4;
  const int qrow0 = b * SEQ + qt * 64;
  // stage Q once
  #pragma unroll
  for (int p = 0; p < 4; p++) {
    const int i = p * 16 + lr;
    *(float4*)&Qs[i][lc] =
        *(const float4*)(qkb + (size_t)(qrow0 + i) * 1024 + h * DH + lc);
  }
  float mrun[4] = {-1e30f, -1e30f, -1e30f, -1e30f};
  float lsum[4] = {0.f, 0.f, 0.f, 0.f};
  float o[4][4] = {};
  for (int kt = 0; kt < 16; kt++) {
    __syncthreads();             // previous PV done before overwriting K/V
    const int krow0 = b * SEQ + kt * 64;
    #pragma unroll
    for (int p = 0; p < 4; p++) {
      const int j = p * 16 + lr;
      const float4 kv =
          *(const float4*)(qkb + (size_t)(krow0 + j) * 1024 + 512 + h * DH + lc);
      *(float4*)&Ks[j][((lc >> 2) ^ (j >> 3)) << 2] = kv;
      *(float4*)&Vs[j][lc] =
          *(const float4*)(vbuf + (size_t)(krow0 + j) * 512 + h * DH + lc);
    }
    __syncthreads();
    // S = Q K^T (4x4 per thread)
    float s[4][4] = {};
    for (int d0 = 0; d0 < 64; d0 += 4) {
      float4 qa[4], kf[4];
      #pragma unroll
      for (int ii = 0; ii < 4; ii++)
        qa[ii] = *(const float4*)&Qs[ty * 4 + ii][d0];
      #pragma unroll
      for (int jj = 0; jj < 4; jj++) {
        const int j = tx * 4 + jj;
        kf[jj] = *(const float4*)&Ks[j][((d0 >> 2) ^ (j >> 3)) << 2];
      }
      #pragma unroll
      for (int ii = 0; ii < 4; ii++)
        #pragma unroll
        for (int jj = 0; jj < 4; jj++)
          s[ii][jj] += qa[ii].x * kf[jj].x + qa[ii].y * kf[jj].y +
                       qa[ii].z * kf[jj].z + qa[ii].w * kf[jj].w;
    }
    // scale + online softmax (rows split across 16 tx lanes, shuffle-reduce)
    #pragma unroll
    for (int ii = 0; ii < 4; ii++) {
      #pragma unroll
      for (int jj = 0; jj < 4; jj++) s[ii][jj] *= 0.125f;
      float mx = fmaxf(fmaxf(s[ii][0], s[ii][1]), fmaxf(s[ii][2], s[ii][3]));
      #pragma unroll
      for (int mk = 1; mk < 16; mk <<= 1) mx = fmaxf(mx, __shfl_xor(mx, mk));
      const float mnew = fmaxf(mrun[ii], mx);
      const float corr = __expf(mrun[ii] - mnew);
      mrun[ii] = mnew;
      float rs = 0.f;
      #pragma unroll
      for (int jj = 0; jj < 4; jj++) {
        const float p = __expf(s[ii][jj] - mnew);
        s[ii][jj] = p;
        rs += p;
      }
      #pragma unroll
      for (int mk = 1; mk < 16; mk <<= 1) rs += __shfl_xor(rs, mk);
      lsum[ii] = lsum[ii] * corr + rs;
      #pragma unroll
      for (int cc = 0; cc < 4; cc++) o[ii][cc] *= corr;
      *(float4*)&Ps[ty * 4 + ii][tx * 4] =
          make_float4(s[ii][0], s[ii][1], s[ii][2], s[ii][3]);
    }
    __syncthreads();
    // O += P V
    for (int j0 = 0; j0 < 64; j0 += 4) {
      float4 pa[4], vf[4];
      #pragma unroll
      for (int ii = 0; ii < 4; ii++)
        pa[ii] = *(const float4*)&Ps[ty * 4 + ii][j0];
      #pragma unroll
      for (int jj = 0; jj < 4; jj++)
        vf[jj] = *(const float4*)&Vs[j0 + jj][tx * 4];
      #pragma unroll
      for (int ii = 0; ii < 4; ii++) {
        o[ii][0] += pa[ii].x * vf[0].x + pa[ii].y * vf[1].x + pa[ii].z * vf[2].x + pa[ii].w * vf[3].x;
        o[ii][1] += pa[ii].x * vf[0].y + pa[ii].y * vf[1].y + pa[ii].z * vf[2].y + pa[ii].w * vf[3].y;
        o[ii][2] += pa[ii].x * vf[0].z + pa[ii].y * vf[1].z + pa[ii].z * vf[2].z + pa[ii].w * vf[3].z;
        o[ii][3] += pa[ii].x * vf[0].w + pa[ii].y * vf[1].w + pa[ii].z * vf[2].w + pa[ii].w * vf[3].w;
      }
    }
  }
  #pragma unroll
  for (int ii = 0; ii < 4; ii++) {
    const float invl = 1.0f / lsum[ii];
    float* op = ao + (size_t)(qrow0 + ty * 4 + ii) * 512 + h * DH + tx * 4;
    *(float4*)op = make_float4(o[ii][0] * invl, o[ii][1] * invl,
                               o[ii][2] * invl, o[ii][3] * invl);
  }
}

extern "C" void kernel_launch(void* const* d_in, const int* in_sizes, int n_in,
                              void* d_out, int out_size, void* d_ws, size_t ws_size,
                              hipStream_t stream) {
  const float* x     = (const float*)d_in[0];
  const float* gamma = (const float*)d_in[1];
  const float* beta  = (const float*)d_in[2];
  const float* W_qk  = (const float*)d_in[3];
  const float* W_v   = (const float*)d_in[4];
  const float* W_out = (const float*)d_in[5];
  float* out = (float*)d_out;
  char* ws = (char*)d_ws;

  float* xn  = (float*)ws;                                   // 16 MiB [8192,512]
  float* qkb = (float*)(ws + (size_t)16 * 1024 * 1024);      // 32 MiB [8192,1024]
  float* vbf = (float*)(ws + (size_t)48 * 1024 * 1024);      // 16 MiB [8192,512]
  float* ao  = xn;  // xn dead after the two projection GEMMs

  ln_kernel<<<TOK, 64, 0, stream>>>(x, gamma, beta, xn);
  sgemm_kernel<<<dim3(1024 / BN, TOK / BM), 256, 0, stream>>>(xn, W_qk, qkb, TOK, 1024, 512);
  sgemm_kernel<<<dim3(512 / BN, TOK / BM), 256, 0, stream>>>(xn, W_v, vbf, TOK, 512, 512);
  flash_kernel<<<dim3(16, 64), 256, 0, stream>>>(qkb, vbf, ao);
  sgemm_kernel<<<dim3(512 / BN, TOK / BM), 256, 0, stream>>>(ao, W_out, out, TOK, 512, 512);
}

// Round 2
// 342.757 us; speedup vs baseline: 2.0727x; 2.0727x over previous
//
#include <hip/hip_runtime.h>

#define TOK 8192       // B*N rows
#define DMODEL 512
#define SEQ 1024
#define NH 8
#define DH 64

typedef _Float16 half8 __attribute__((ext_vector_type(8)));
typedef _Float16 half4v __attribute__((ext_vector_type(4)));
typedef float floatx4 __attribute__((ext_vector_type(4)));

// ---------------- LayerNorm: one wave per row ----------------
__global__ __launch_bounds__(64) void ln_kernel(
    const float* __restrict__ x, const float* __restrict__ gamma,
    const float* __restrict__ beta, float* __restrict__ xn) {
  const int row = blockIdx.x;
  const int t = threadIdx.x;
  const float* xr = x + (size_t)row * DMODEL;
  const float4 a = *(const float4*)(xr + t * 4);
  const float4 b = *(const float4*)(xr + 256 + t * 4);
  float s  = a.x + a.y + a.z + a.w + b.x + b.y + b.z + b.w;
  float ss = a.x*a.x + a.y*a.y + a.z*a.z + a.w*a.w
           + b.x*b.x + b.y*b.y + b.z*b.z + b.w*b.w;
  #pragma unroll
  for (int m = 1; m < 64; m <<= 1) {
    s  += __shfl_xor(s, m);
    ss += __shfl_xor(ss, m);
  }
  const float mean = s * (1.0f / DMODEL);
  const float var  = ss * (1.0f / DMODEL) - mean * mean;
  const float inv  = rsqrtf(var + 1e-5f);
  const float4 g0  = *(const float4*)(gamma + t * 4);
  const float4 g1  = *(const float4*)(gamma + 256 + t * 4);
  const float4 be0 = *(const float4*)(beta + t * 4);
  const float4 be1 = *(const float4*)(beta + 256 + t * 4);
  float4 o0, o1;
  o0.x = (a.x - mean) * inv * g0.x + be0.x;
  o0.y = (a.y - mean) * inv * g0.y + be0.y;
  o0.z = (a.z - mean) * inv * g0.z + be0.z;
  o0.w = (a.w - mean) * inv * g0.w + be0.w;
  o1.x = (b.x - mean) * inv * g1.x + be1.x;
  o1.y = (b.y - mean) * inv * g1.y + be1.y;
  o1.z = (b.z - mean) * inv * g1.z + be1.z;
  o1.w = (b.w - mean) * inv * g1.w + be1.w;
  float* outr = xn + (size_t)row * DMODEL;
  *(float4*)(outr + t * 4) = o0;
  *(float4*)(outr + 256 + t * 4) = o1;
}

// ---------------- fp32 SGEMM core, templated epilogue ----------------
// MODE 0: fp32 store C[M,N]
// MODE 1: f16 store C[M,N]
// MODE 2: f16 transposed store vt[((b*8+h)*64+d)*1024 + tok]  (N must be 512)
#define BM 128
#define BN 128
#define BK 8

template <int MODE>
__global__ __launch_bounds__(256) void sgemm_kernel(
    const float* __restrict__ A, const float* __restrict__ B,
    void* __restrict__ Cout, int M, int N, int K) {
  __shared__ float As[BK][BM];   // A tile stored transposed: As[k][m]
  __shared__ float Bs[BK][BN];
  const int bn = blockIdx.x, bm = blockIdx.y;
  const int tid = threadIdx.x;
  const int ry = tid >> 4, rx = tid & 15;      // 16x16 threads, 8x8 micro-tile
  const int am = tid >> 1, ak = (tid & 1) * 4; // A staging coords
  const int bkr = tid >> 5, bnc = (tid & 31) * 4;
  const float* Ap = A + (size_t)(bm * BM + am) * K + ak;
  const float* Bp = B + (size_t)bkr * N + bn * BN + bnc;
  float acc[8][8] = {};
  for (int k0 = 0; k0 < K; k0 += BK) {
    const float4 av = *(const float4*)(Ap + k0);
    const float4 bv = *(const float4*)(Bp + (size_t)k0 * N);
    As[ak + 0][am] = av.x;
    As[ak + 1][am] = av.y;
    As[ak + 2][am] = av.z;
    As[ak + 3][am] = av.w;
    *(float4*)&Bs[bkr][bnc] = bv;
    __syncthreads();
    #pragma unroll
    for (int kk = 0; kk < BK; kk++) {
      float a[8], b[8];
      *(float4*)(a)     = *(const float4*)&As[kk][ry * 8];
      *(float4*)(a + 4) = *(const float4*)&As[kk][ry * 8 + 4];
      *(float4*)(b)     = *(const float4*)&Bs[kk][rx * 8];
      *(float4*)(b + 4) = *(const float4*)&Bs[kk][rx * 8 + 4];
      #pragma unroll
      for (int i = 0; i < 8; i++)
        #pragma unroll
        for (int j = 0; j < 8; j++)
          acc[i][j] = fmaf(a[i], b[j], acc[i][j]);
    }
    __syncthreads();
  }
  const int crow0 = bm * BM + ry * 8;
  const int ccol0 = bn * BN + rx * 8;
  if constexpr (MODE == 0) {
    float* C = (float*)Cout;
    #pragma unroll
    for (int i = 0; i < 8; i++) {
      float* cp = C + (size_t)(crow0 + i) * N + ccol0;
      *(float4*)cp       = make_float4(acc[i][0], acc[i][1], acc[i][2], acc[i][3]);
      *(float4*)(cp + 4) = make_float4(acc[i][4], acc[i][5], acc[i][6], acc[i][7]);
    }
  } else if constexpr (MODE == 1) {
    _Float16* C = (_Float16*)Cout;
    #pragma unroll
    for (int i = 0; i < 8; i++) {
      half8 h;
      #pragma unroll
      for (int j = 0; j < 8; j++) h[j] = (_Float16)acc[i][j];
      *(half8*)(C + (size_t)(crow0 + i) * N + ccol0) = h;
    }
  } else {
    _Float16* C = (_Float16*)Cout;
    const int tok = crow0 & 1023;          // 8 consecutive tokens
    const int bb = crow0 >> 10;
    #pragma unroll
    for (int j = 0; j < 8; j++) {
      const int col = ccol0 + j;
      half8 h;
      #pragma unroll
      for (int i = 0; i < 8; i++) h[i] = (_Float16)acc[i][j];
      *(half8*)(C + ((size_t)((bb * 8 + (col >> 6)) * 64 + (col & 63)) << 10) + tok) = h;
    }
  }
}

// ---------------- flash attention, fp16 MFMA ----------------
// qkh: [8192,1024] f16, cols [h*64+d]=q, [512+h*64+d]=k
// vt:  [(b*8+h)*64+d][1024] f16 (V transposed per head)
// ao:  [8192,512] fp32, b n (h d)
__global__ __launch_bounds__(256) void flash16_kernel(
    const _Float16* __restrict__ qkh, const _Float16* __restrict__ vt,
    float* __restrict__ ao) {
  __shared__ char smem[24576];   // Ks 8K | Vt 8K | P 4x2K
  const int qt = blockIdx.x;     // 0..15
  const int bh = blockIdx.y;     // 0..63
  const int b = bh >> 3, h = bh & 7;
  const int tid = threadIdx.x;
  const int wv = tid >> 6, lane = tid & 63;
  const int l15 = lane & 15, g = lane >> 4;
  const int swz = (l15 & 7) << 4;
  const int qrow0 = b * SEQ + qt * 64;

  // Q fragments (B operand), loaded once: n = l15 (q row), k = g*8+i (+32*kk)
  half8 qf[2];
  {
    const _Float16* qp = qkh + (size_t)(qrow0 + wv * 16 + l15) * 1024 + h * DH;
    qf[0] = *(const half8*)(qp + g * 8);
    qf[1] = *(const half8*)(qp + g * 8 + 32);
  }

  float mrun = -1e30f, lsum = 0.f;
  floatx4 oacc[4] = {};

  const int sr = tid >> 3;          // staging row 0..31 (+32 second pass)
  const int scb = (tid & 7) * 16;   // byte offset of 8-half chunk in row
  const _Float16* kbase = qkh + 512 + h * DH;
  const _Float16* vbase = vt + (size_t)bh * 64 * 1024;
  char* pb = smem + 16384 + wv * 2048 + l15 * 128;   // per-wave P strip

  for (int kt = 0; kt < 16; ++kt) {
    __syncthreads();               // prior tile's MFMA reads done
    const int krow0 = b * SEQ + kt * 64;
    #pragma unroll
    for (int p = 0; p < 2; ++p) {
      const int r = sr + p * 32;
      const int wsw = scb ^ ((r & 7) << 4);
      half8 kv = *(const half8*)(kbase + (size_t)(krow0 + r) * 1024 + (scb >> 1));
      *(half8*)(smem + r * 128 + wsw) = kv;
      half8 vv = *(const half8*)(vbase + r * 1024 + kt * 64 + (scb >> 1));
      *(half8*)(smem + 8192 + r * 128 + wsw) = vv;
    }
    __syncthreads();

    // S^T[k][q] = mfma(A=K, B=Q): m = kcol = 16*mt + l15, k-dim = d
    floatx4 sacc[4] = {};
    #pragma unroll
    for (int kk = 0; kk < 2; ++kk) {
      #pragma unroll
      for (int mt = 0; mt < 4; ++mt) {
        half8 af = *(const half8*)(smem + (16 * mt + l15) * 128 +
                                   ((g * 16 + kk * 64) ^ swz));
        sacc[mt] = __builtin_amdgcn_mfma_f32_16x16x32_f16(af, qf[kk], sacc[mt], 0, 0, 0);
      }
    }

    // online softmax: lane holds 16 S values of row q=l15 (k = 16*mt+4*g+reg)
    float s[16];
    #pragma unroll
    for (int mt = 0; mt < 4; ++mt)
      #pragma unroll
      for (int r = 0; r < 4; ++r) s[mt * 4 + r] = sacc[mt][r] * 0.125f;
    float mx = s[0];
    #pragma unroll
    for (int i = 1; i < 16; ++i) mx = fmaxf(mx, s[i]);
    mx = fmaxf(mx, __shfl_xor(mx, 16));
    mx = fmaxf(mx, __shfl_xor(mx, 32));
    const float mnew = fmaxf(mrun, mx);
    const float corr = __expf(mrun - mnew);
    float rs = 0.f;
    #pragma unroll
    for (int i = 0; i < 16; ++i) {
      s[i] = __expf(s[i] - mnew);
      rs += s[i];
    }
    rs += __shfl_xor(rs, 16);
    rs += __shfl_xor(rs, 32);
    lsum = lsum * corr + rs;
    mrun = mnew;
    #pragma unroll
    for (int mt = 0; mt < 4; ++mt) oacc[mt] *= corr;

    // P -> per-wave LDS strip, layout P[q][k] f16, swizzled
    #pragma unroll
    for (int mt = 0; mt < 4; ++mt) {
      half4v pv;
      pv[0] = (_Float16)s[mt * 4 + 0];
      pv[1] = (_Float16)s[mt * 4 + 1];
      pv[2] = (_Float16)s[mt * 4 + 2];
      pv[3] = (_Float16)s[mt * 4 + 3];
      *(half4v*)(pb + ((32 * mt + 8 * g) ^ swz)) = pv;
    }
    // same-wave LDS write->read: no barrier needed

    // O^T[d][q] += mfma(A=Vt, B=P^T): m = d = 16*mt + l15, k-dim = ktoken
    #pragma unroll
    for (int kk = 0; kk < 2; ++kk) {
      half8 pf = *(const half8*)(pb + ((g * 16 + kk * 64) ^ swz));
      #pragma unroll
      for (int mt = 0; mt < 4; ++mt) {
        half8 vf = *(const half8*)(smem + 8192 + (16 * mt + l15) * 128 +
                                   ((g * 16 + kk * 64) ^ swz));
        oacc[mt] = __builtin_amdgcn_mfma_f32_16x16x32_f16(vf, pf, oacc[mt], 0, 0, 0);
      }
    }
  }

  const float inv = 1.0f / lsum;
  float* op = ao + (size_t)(qrow0 + wv * 16 + l15) * 512 + h * DH;
  #pragma unroll
  for (int mt = 0; mt < 4; ++mt) {
    float4 st = make_float4(oacc[mt][0] * inv, oacc[mt][1] * inv,
                            oacc[mt][2] * inv, oacc[mt][3] * inv);
    *(float4*)(op + 16 * mt + 4 * g) = st;
  }
}

extern "C" void kernel_launch(void* const* d_in, const int* in_sizes, int n_in,
                              void* d_out, int out_size, void* d_ws, size_t ws_size,
                              hipStream_t stream) {
  const float* x     = (const float*)d_in[0];
  const float* gamma = (const float*)d_in[1];
  const float* beta  = (const float*)d_in[2];
  const float* W_qk  = (const float*)d_in[3];
  const float* W_v   = (const float*)d_in[4];
  const float* W_out = (const float*)d_in[5];
  float* out = (float*)d_out;
  char* ws = (char*)d_ws;

  float*     xn  = (float*)ws;                               // 16 MiB [8192,512] f32
  _Float16*  qkh = (_Float16*)(ws + (size_t)16 * 1024 * 1024); // 16 MiB [8192,1024] f16
  _Float16*  vtb = (_Float16*)(ws + (size_t)32 * 1024 * 1024); // 8 MiB  [64*64,1024] f16
  float*     ao  = xn;  // xn dead after the two projection GEMMs

  ln_kernel<<<TOK, 64, 0, stream>>>(x, gamma, beta, xn);
  sgemm_kernel<1><<<dim3(1024 / BN, TOK / BM), 256, 0, stream>>>(xn, W_qk, qkh, TOK, 1024, 512);
  sgemm_kernel<2><<<dim3(512 / BN, TOK / BM), 256, 0, stream>>>(xn, W_v, vtb, TOK, 512, 512);
  flash16_kernel<<<dim3(16, 64), 256, 0, stream>>>(qkh, vtb, ao);
  sgemm_kernel<0><<<dim3(512 / BN, TOK / BM), 256, 0, stream>>>(ao, W_out, out, TOK, 512, 512);
}

// Round 3
// 104.405 us; speedup vs baseline: 6.8047x; 3.2830x over previous
//
#include <hip/hip_runtime.h>

#define TOK 8192       // B*N rows
#define DMODEL 512
#define SEQ 1024
#define NH 8
#define DH 64

typedef _Float16 half8 __attribute__((ext_vector_type(8)));
typedef _Float16 half4v __attribute__((ext_vector_type(4)));
typedef float floatx4 __attribute__((ext_vector_type(4)));

// ---------------- LayerNorm: one wave per row, f16 output ----------------
__global__ __launch_bounds__(64) void ln_kernel(
    const float* __restrict__ x, const float* __restrict__ gamma,
    const float* __restrict__ beta, _Float16* __restrict__ xn) {
  const int row = blockIdx.x;
  const int t = threadIdx.x;
  const float* xr = x + (size_t)row * DMODEL;
  const float4 a = *(const float4*)(xr + t * 4);
  const float4 b = *(const float4*)(xr + 256 + t * 4);
  float s  = a.x + a.y + a.z + a.w + b.x + b.y + b.z + b.w;
  float ss = a.x*a.x + a.y*a.y + a.z*a.z + a.w*a.w
           + b.x*b.x + b.y*b.y + b.z*b.z + b.w*b.w;
  #pragma unroll
  for (int m = 1; m < 64; m <<= 1) {
    s  += __shfl_xor(s, m);
    ss += __shfl_xor(ss, m);
  }
  const float mean = s * (1.0f / DMODEL);
  const float var  = ss * (1.0f / DMODEL) - mean * mean;
  const float inv  = rsqrtf(var + 1e-5f);
  const float4 g0  = *(const float4*)(gamma + t * 4);
  const float4 g1  = *(const float4*)(gamma + 256 + t * 4);
  const float4 be0 = *(const float4*)(beta + t * 4);
  const float4 be1 = *(const float4*)(beta + 256 + t * 4);
  half4v o0, o1;
  o0[0] = (_Float16)((a.x - mean) * inv * g0.x + be0.x);
  o0[1] = (_Float16)((a.y - mean) * inv * g0.y + be0.y);
  o0[2] = (_Float16)((a.z - mean) * inv * g0.z + be0.z);
  o0[3] = (_Float16)((a.w - mean) * inv * g0.w + be0.w);
  o1[0] = (_Float16)((b.x - mean) * inv * g1.x + be1.x);
  o1[1] = (_Float16)((b.y - mean) * inv * g1.y + be1.y);
  o1[2] = (_Float16)((b.z - mean) * inv * g1.z + be1.z);
  o1[3] = (_Float16)((b.w - mean) * inv * g1.w + be1.w);
  _Float16* outr = xn + (size_t)row * DMODEL;
  *(half4v*)(outr + t * 4) = o0;
  *(half4v*)(outr + 256 + t * 4) = o1;
}

// ---------------- W[K][N] fp32 -> WT[N][K] f16 ----------------
__global__ __launch_bounds__(256) void transpose_cvt_kernel(
    const float* __restrict__ W, _Float16* __restrict__ WT, int K, int N) {
  __shared__ float t[32][33];
  const int tx = threadIdx.x & 31, ty = threadIdx.x >> 5;
  const int n0 = blockIdx.x * 32, k0 = blockIdx.y * 32;
  #pragma unroll
  for (int j = 0; j < 4; ++j)
    t[ty + j * 8][tx] = W[(size_t)(k0 + ty + j * 8) * N + n0 + tx];
  __syncthreads();
  #pragma unroll
  for (int j = 0; j < 4; ++j)
    WT[(size_t)(n0 + ty + j * 8) * K + k0 + tx] = (_Float16)t[tx][ty + j * 8];
}

// ---------------- f16 MFMA GEMM: C[M,N] = A[M,K] * Bt[N,K]^T ----------------
// MODE 0: fp32 C[M,N]   MODE 1: f16 C[M,N]
// MODE 2: f16 vt store: vt[((tok>>10)*8 + col>>6)*64 + (col&63)][tok&1023]
template <int MODE>
__global__ __launch_bounds__(256) void hgemm_kernel(
    const _Float16* __restrict__ A, const _Float16* __restrict__ Bt,
    void* __restrict__ Cout, int M, int N, int K) {
  __shared__ char smem[32768];  // As [128 rows][128B] | Bs [128 rows][128B]
  const int tid = threadIdx.x;
  const int bn = blockIdx.x, bm = blockIdx.y;
  const int wv = tid >> 6, lane = tid & 63;
  const int l15 = lane & 15, g = lane >> 4;
  const int wr = wv >> 1, wc = wv & 1;
  const int swz = (l15 & 7) << 4;
  const _Float16* Ab = A + (size_t)(bm * 128) * K;
  const _Float16* Bb = Bt + (size_t)(bn * 128) * K;
  const int srow_b = tid >> 3;       // 0..31 (+32p)
  const int scb = (tid & 7) * 16;    // byte chunk within 128B row

  floatx4 acc[4][4] = {};
  for (int kt = 0; kt < K; kt += 64) {
    __syncthreads();
    #pragma unroll
    for (int p = 0; p < 4; ++p) {
      const int row = p * 32 + srow_b;
      const int w = scb ^ ((row & 7) << 4);
      *(half8*)(smem + row * 128 + w) =
          *(const half8*)(Ab + (size_t)row * K + kt + (scb >> 1));
      *(half8*)(smem + 16384 + row * 128 + w) =
          *(const half8*)(Bb + (size_t)row * K + kt + (scb >> 1));
    }
    __syncthreads();
    #pragma unroll
    for (int kk = 0; kk < 2; ++kk) {
      half8 af[4], bf[4];
      #pragma unroll
      for (int mt = 0; mt < 4; ++mt)
        af[mt] = *(const half8*)(smem + (wr * 64 + mt * 16 + l15) * 128 +
                                 ((g * 16 + kk * 64) ^ swz));
      #pragma unroll
      for (int nt = 0; nt < 4; ++nt)
        bf[nt] = *(const half8*)(smem + 16384 + (wc * 64 + nt * 16 + l15) * 128 +
                                 ((g * 16 + kk * 64) ^ swz));
      #pragma unroll
      for (int mt = 0; mt < 4; ++mt)
        #pragma unroll
        for (int nt = 0; nt < 4; ++nt)
          acc[mt][nt] = __builtin_amdgcn_mfma_f32_16x16x32_f16(
              af[mt], bf[nt], acc[mt][nt], 0, 0, 0);
    }
  }
  const int m0 = bm * 128 + wr * 64;
  const int n0 = bn * 128 + wc * 64;
  if constexpr (MODE == 0) {
    float* C = (float*)Cout;
    #pragma unroll
    for (int mt = 0; mt < 4; ++mt)
      #pragma unroll
      for (int nt = 0; nt < 4; ++nt) {
        const int n = n0 + nt * 16 + l15;
        #pragma unroll
        for (int r = 0; r < 4; ++r)
          C[(size_t)(m0 + mt * 16 + 4 * g + r) * N + n] = acc[mt][nt][r];
      }
  } else if constexpr (MODE == 1) {
    _Float16* C = (_Float16*)Cout;
    #pragma unroll
    for (int mt = 0; mt < 4; ++mt)
      #pragma unroll
      for (int nt = 0; nt < 4; ++nt) {
        const int n = n0 + nt * 16 + l15;
        #pragma unroll
        for (int r = 0; r < 4; ++r)
          C[(size_t)(m0 + mt * 16 + 4 * g + r) * N + n] = (_Float16)acc[mt][nt][r];
      }
  } else {
    _Float16* C = (_Float16*)Cout;
    #pragma unroll
    for (int mt = 0; mt < 4; ++mt) {
      const int mrow = m0 + mt * 16 + 4 * g;   // 4-aligned token
      const int b = mrow >> 10, tok = mrow & 1023;
      #pragma unroll
      for (int nt = 0; nt < 4; ++nt) {
        const int col = n0 + nt * 16 + l15;
        half4v hv;
        #pragma unroll
        for (int r = 0; r < 4; ++r) hv[r] = (_Float16)acc[mt][nt][r];
        *(half4v*)(C + ((size_t)((b * 8 + (col >> 6)) * 64 + (col & 63)) << 10) + tok) = hv;
      }
    }
  }
}

// ---------------- flash attention, fp16 MFMA ----------------
// qkh: [8192,1024] f16, cols [h*64+d]=q, [512+h*64+d]=k
// vt:  [(b*8+h)*64+d][1024] f16 (V transposed per head)
// ao:  [8192,512] f16, b n (h d)
__global__ __launch_bounds__(256) void flash16_kernel(
    const _Float16* __restrict__ qkh, const _Float16* __restrict__ vt,
    _Float16* __restrict__ ao) {
  __shared__ char smem[24576];   // Ks 8K | Vt 8K | P 4x2K
  const int qt = blockIdx.x;     // 0..15
  const int bh = blockIdx.y;     // 0..63
  const int b = bh >> 3, h = bh & 7;
  const int tid = threadIdx.x;
  const int wv = tid >> 6, lane = tid & 63;
  const int l15 = lane & 15, g = lane >> 4;
  const int swz = (l15 & 7) << 4;
  const int qrow0 = b * SEQ + qt * 64;

  half8 qf[2];
  {
    const _Float16* qp = qkh + (size_t)(qrow0 + wv * 16 + l15) * 1024 + h * DH;
    qf[0] = *(const half8*)(qp + g * 8);
    qf[1] = *(const half8*)(qp + g * 8 + 32);
  }

  float mrun = -1e30f, lsum = 0.f;
  floatx4 oacc[4] = {};

  const int sr = tid >> 3;          // staging row 0..31 (+32 second pass)
  const int scb = (tid & 7) * 16;   // byte offset of 8-half chunk in row
  const _Float16* kbase = qkh + 512 + h * DH;
  const _Float16* vbase = vt + (size_t)bh * 64 * 1024;
  char* pb = smem + 16384 + wv * 2048 + l15 * 128;   // per-wave P strip

  for (int kt = 0; kt < 16; ++kt) {
    __syncthreads();               // prior tile's MFMA reads done
    const int krow0 = b * SEQ + kt * 64;
    #pragma unroll
    for (int p = 0; p < 2; ++p) {
      const int r = sr + p * 32;
      const int wsw = scb ^ ((r & 7) << 4);
      half8 kv = *(const half8*)(kbase + (size_t)(krow0 + r) * 1024 + (scb >> 1));
      *(half8*)(smem + r * 128 + wsw) = kv;
      half8 vv = *(const half8*)(vbase + r * 1024 + kt * 64 + (scb >> 1));
      *(half8*)(smem + 8192 + r * 128 + wsw) = vv;
    }
    __syncthreads();

    // S^T[k][q] = mfma(A=K, B=Q)
    floatx4 sacc[4] = {};
    #pragma unroll
    for (int kk = 0; kk < 2; ++kk) {
      #pragma unroll
      for (int mt = 0; mt < 4; ++mt) {
        half8 af = *(const half8*)(smem + (16 * mt + l15) * 128 +
                                   ((g * 16 + kk * 64) ^ swz));
        sacc[mt] = __builtin_amdgcn_mfma_f32_16x16x32_f16(af, qf[kk], sacc[mt], 0, 0, 0);
      }
    }

    float s[16];
    #pragma unroll
    for (int mt = 0; mt < 4; ++mt)
      #pragma unroll
      for (int r = 0; r < 4; ++r) s[mt * 4 + r] = sacc[mt][r] * 0.125f;
    float mx = s[0];
    #pragma unroll
    for (int i = 1; i < 16; ++i) mx = fmaxf(mx, s[i]);
    mx = fmaxf(mx, __shfl_xor(mx, 16));
    mx = fmaxf(mx, __shfl_xor(mx, 32));
    const float mnew = fmaxf(mrun, mx);
    const float corr = __expf(mrun - mnew);
    float rs = 0.f;
    #pragma unroll
    for (int i = 0; i < 16; ++i) {
      s[i] = __expf(s[i] - mnew);
      rs += s[i];
    }
    rs += __shfl_xor(rs, 16);
    rs += __shfl_xor(rs, 32);
    lsum = lsum * corr + rs;
    mrun = mnew;
    #pragma unroll
    for (int mt = 0; mt < 4; ++mt) oacc[mt] *= corr;

    #pragma unroll
    for (int mt = 0; mt < 4; ++mt) {
      half4v pv;
      pv[0] = (_Float16)s[mt * 4 + 0];
      pv[1] = (_Float16)s[mt * 4 + 1];
      pv[2] = (_Float16)s[mt * 4 + 2];
      pv[3] = (_Float16)s[mt * 4 + 3];
      *(half4v*)(pb + ((32 * mt + 8 * g) ^ swz)) = pv;
    }

    // O^T[d][q] += mfma(A=Vt, B=P^T)
    #pragma unroll
    for (int kk = 0; kk < 2; ++kk) {
      half8 pf = *(const half8*)(pb + ((g * 16 + kk * 64) ^ swz));
      #pragma unroll
      for (int mt = 0; mt < 4; ++mt) {
        half8 vf = *(const half8*)(smem + 8192 + (16 * mt + l15) * 128 +
                                   ((g * 16 + kk * 64) ^ swz));
        oacc[mt] = __builtin_amdgcn_mfma_f32_16x16x32_f16(vf, pf, oacc[mt], 0, 0, 0);
      }
    }
  }

  const float inv = 1.0f / lsum;
  _Float16* op = ao + (size_t)(qrow0 + wv * 16 + l15) * 512 + h * DH;
  #pragma unroll
  for (int mt = 0; mt < 4; ++mt) {
    half4v hv;
    hv[0] = (_Float16)(oacc[mt][0] * inv);
    hv[1] = (_Float16)(oacc[mt][1] * inv);
    hv[2] = (_Float16)(oacc[mt][2] * inv);
    hv[3] = (_Float16)(oacc[mt][3] * inv);
    *(half4v*)(op + 16 * mt + 4 * g) = hv;
  }
}

extern "C" void kernel_launch(void* const* d_in, const int* in_sizes, int n_in,
                              void* d_out, int out_size, void* d_ws, size_t ws_size,
                              hipStream_t stream) {
  const float* x     = (const float*)d_in[0];
  const float* gamma = (const float*)d_in[1];
  const float* beta  = (const float*)d_in[2];
  const float* W_qk  = (const float*)d_in[3];
  const float* W_v   = (const float*)d_in[4];
  const float* W_out = (const float*)d_in[5];
  float* out = (float*)d_out;
  char* ws = (char*)d_ws;

  const size_t MB = 1024 * 1024;
  _Float16* xn16  = (_Float16*)ws;                    //  8 MiB [8192,512]
  _Float16* qkh   = (_Float16*)(ws + 8 * MB);         // 16 MiB [8192,1024]
  _Float16* vt    = (_Float16*)(ws + 24 * MB);        //  8 MiB [512,1024] per-head T
  _Float16* ao16  = (_Float16*)(ws + 32 * MB);        //  8 MiB [8192,512]
  _Float16* WqkT  = (_Float16*)(ws + 40 * MB);        //  1 MiB [1024,512]
  _Float16* WvT   = (_Float16*)(ws + 41 * MB);        // .5 MiB [512,512]
  _Float16* WoutT = (_Float16*)(ws + 41 * MB + 512 * 1024); // .5 MiB [512,512]

  transpose_cvt_kernel<<<dim3(32, 16), 256, 0, stream>>>(W_qk, WqkT, 512, 1024);
  transpose_cvt_kernel<<<dim3(16, 16), 256, 0, stream>>>(W_v, WvT, 512, 512);
  transpose_cvt_kernel<<<dim3(16, 16), 256, 0, stream>>>(W_out, WoutT, 512, 512);
  ln_kernel<<<TOK, 64, 0, stream>>>(x, gamma, beta, xn16);
  hgemm_kernel<1><<<dim3(8, 64), 256, 0, stream>>>(xn16, WqkT, qkh, TOK, 1024, 512);
  hgemm_kernel<2><<<dim3(4, 64), 256, 0, stream>>>(xn16, WvT, vt, TOK, 512, 512);
  flash16_kernel<<<dim3(16, 64), 256, 0, stream>>>(qkh, vt, ao16);
  hgemm_kernel<0><<<dim3(4, 64), 256, 0, stream>>>(ao16, WoutT, out, TOK, 512, 512);
}

// Round 4
// 100.467 us; speedup vs baseline: 7.0714x; 1.0392x over previous
//
#include <hip/hip_runtime.h>

#define TOK 8192       // B*N rows
#define DMODEL 512
#define SEQ 1024
#define NH 8
#define DH 64

typedef _Float16 half8 __attribute__((ext_vector_type(8)));
typedef _Float16 half4v __attribute__((ext_vector_type(4)));
typedef float floatx4 __attribute__((ext_vector_type(4)));

__device__ __forceinline__ void gll16(const void* g, void* l) {
  __builtin_amdgcn_global_load_lds(
      (const __attribute__((address_space(1))) void*)g,
      (__attribute__((address_space(3))) void*)l, 16, 0, 0);
}

// ---------------- LayerNorm: one wave per row, f16 output ----------------
__global__ __launch_bounds__(256) void ln_kernel(
    const float* __restrict__ x, const float* __restrict__ gamma,
    const float* __restrict__ beta, _Float16* __restrict__ xn) {
  const int row = blockIdx.x * 4 + (threadIdx.x >> 6);
  const int t = threadIdx.x & 63;
  const float* xr = x + (size_t)row * DMODEL;
  const float4 a = *(const float4*)(xr + t * 4);
  const float4 b = *(const float4*)(xr + 256 + t * 4);
  float s  = a.x + a.y + a.z + a.w + b.x + b.y + b.z + b.w;
  float ss = a.x*a.x + a.y*a.y + a.z*a.z + a.w*a.w
           + b.x*b.x + b.y*b.y + b.z*b.z + b.w*b.w;
  #pragma unroll
  for (int m = 1; m < 64; m <<= 1) {
    s  += __shfl_xor(s, m);
    ss += __shfl_xor(ss, m);
  }
  const float mean = s * (1.0f / DMODEL);
  const float var  = ss * (1.0f / DMODEL) - mean * mean;
  const float inv  = rsqrtf(var + 1e-5f);
  const float4 g0  = *(const float4*)(gamma + t * 4);
  const float4 g1  = *(const float4*)(gamma + 256 + t * 4);
  const float4 be0 = *(const float4*)(beta + t * 4);
  const float4 be1 = *(const float4*)(beta + 256 + t * 4);
  half4v o0, o1;
  o0[0] = (_Float16)((a.x - mean) * inv * g0.x + be0.x);
  o0[1] = (_Float16)((a.y - mean) * inv * g0.y + be0.y);
  o0[2] = (_Float16)((a.z - mean) * inv * g0.z + be0.z);
  o0[3] = (_Float16)((a.w - mean) * inv * g0.w + be0.w);
  o1[0] = (_Float16)((b.x - mean) * inv * g1.x + be1.x);
  o1[1] = (_Float16)((b.y - mean) * inv * g1.y + be1.y);
  o1[2] = (_Float16)((b.z - mean) * inv * g1.z + be1.z);
  o1[3] = (_Float16)((b.w - mean) * inv * g1.w + be1.w);
  _Float16* outr = xn + (size_t)row * DMODEL;
  *(half4v*)(outr + t * 4) = o0;
  *(half4v*)(outr + 256 + t * 4) = o1;
}

// ---------------- W[K][N] fp32 -> WT[N][K] f16 ----------------
__global__ __launch_bounds__(256) void transpose_cvt_kernel(
    const float* __restrict__ W, _Float16* __restrict__ WT, int K, int N) {
  __shared__ float t[32][33];
  const int tx = threadIdx.x & 31, ty = threadIdx.x >> 5;
  const int n0 = blockIdx.x * 32, k0 = blockIdx.y * 32;
  #pragma unroll
  for (int j = 0; j < 4; ++j)
    t[ty + j * 8][tx] = W[(size_t)(k0 + ty + j * 8) * N + n0 + tx];
  __syncthreads();
  #pragma unroll
  for (int j = 0; j < 4; ++j)
    WT[(size_t)(n0 + ty + j * 8) * K + k0 + tx] = (_Float16)t[tx][ty + j * 8];
}

// ---------------- f16 MFMA GEMM: C[M,N] = A[M,K] * Bt[N,K]^T ----------------
// global_load_lds staging: linear LDS, pre-swizzled global source, swizzled read.
// MODE 0: fp32 C[M,N]   MODE 1: f16 C[M,N]
// MODE 2: f16 vt store: vt[((tok>>10)*8 + col>>6)*64 + (col&63)][tok&1023]
template <int MODE>
__global__ __launch_bounds__(256) void hgemm_kernel(
    const _Float16* __restrict__ A, const _Float16* __restrict__ Bt,
    void* __restrict__ Cout, int M, int N, int K) {
  __shared__ char smem[32768];  // As [128 rows][128B] | Bs [128 rows][128B]
  const int tid = threadIdx.x;
  const int bn = blockIdx.x, bm = blockIdx.y;
  const int wv = tid >> 6, lane = tid & 63;
  const int l15 = lane & 15, g = lane >> 4;
  const int wr = wv >> 1, wc = wv & 1;
  const int swz = (l15 & 7) << 4;
  const _Float16* Ab = A + (size_t)(bm * 128) * K;
  const _Float16* Bb = Bt + (size_t)(bn * 128) * K;
  const int lrow = lane >> 3;          // 0..7
  const int lchk = (lane & 7) * 16;    // byte chunk
  const int ssw = lchk ^ (lrow << 4);  // pre-swizzled source byte offset

  floatx4 acc[4][4] = {};
  for (int kt = 0; kt < K; kt += 64) {
    #pragma unroll
    for (int i = 0; i < 4; ++i) {
      const int row = wv * 32 + i * 8 + lrow;
      gll16((const char*)(Ab + (size_t)row * K + kt) + ssw,
            smem + (wv * 32 + i * 8) * 128);
      gll16((const char*)(Bb + (size_t)row * K + kt) + ssw,
            smem + 16384 + (wv * 32 + i * 8) * 128);
    }
    __syncthreads();   // drains vmcnt -> tiles resident
    #pragma unroll
    for (int kk = 0; kk < 2; ++kk) {
      half8 af[4], bf[4];
      #pragma unroll
      for (int mt = 0; mt < 4; ++mt)
        af[mt] = *(const half8*)(smem + (wr * 64 + mt * 16 + l15) * 128 +
                                 ((g * 16 + kk * 64) ^ swz));
      #pragma unroll
      for (int nt = 0; nt < 4; ++nt)
        bf[nt] = *(const half8*)(smem + 16384 + (wc * 64 + nt * 16 + l15) * 128 +
                                 ((g * 16 + kk * 64) ^ swz));
      #pragma unroll
      for (int mt = 0; mt < 4; ++mt)
        #pragma unroll
        for (int nt = 0; nt < 4; ++nt)
          acc[mt][nt] = __builtin_amdgcn_mfma_f32_16x16x32_f16(
              af[mt], bf[nt], acc[mt][nt], 0, 0, 0);
    }
    __syncthreads();   // reads done before next stage overwrites
  }
  const int m0 = bm * 128 + wr * 64;
  const int n0 = bn * 128 + wc * 64;
  if constexpr (MODE == 0) {
    float* C = (float*)Cout;
    #pragma unroll
    for (int mt = 0; mt < 4; ++mt)
      #pragma unroll
      for (int nt = 0; nt < 4; ++nt) {
        const int n = n0 + nt * 16 + l15;
        #pragma unroll
        for (int r = 0; r < 4; ++r)
          C[(size_t)(m0 + mt * 16 + 4 * g + r) * N + n] = acc[mt][nt][r];
      }
  } else if constexpr (MODE == 1) {
    _Float16* C = (_Float16*)Cout;
    #pragma unroll
    for (int mt = 0; mt < 4; ++mt)
      #pragma unroll
      for (int nt = 0; nt < 4; ++nt) {
        const int n = n0 + nt * 16 + l15;
        #pragma unroll
        for (int r = 0; r < 4; ++r)
          C[(size_t)(m0 + mt * 16 + 4 * g + r) * N + n] = (_Float16)acc[mt][nt][r];
      }
  } else {
    _Float16* C = (_Float16*)Cout;
    #pragma unroll
    for (int mt = 0; mt < 4; ++mt) {
      const int mrow = m0 + mt * 16 + 4 * g;   // 4-aligned token
      const int b = mrow >> 10, tok = mrow & 1023;
      #pragma unroll
      for (int nt = 0; nt < 4; ++nt) {
        const int col = n0 + nt * 16 + l15;
        half4v hv;
        #pragma unroll
        for (int r = 0; r < 4; ++r) hv[r] = (_Float16)acc[mt][nt][r];
        *(half4v*)(C + ((size_t)((b * 8 + (col >> 6)) * 64 + (col & 63)) << 10) + tok) = hv;
      }
    }
  }
}

// ---------------- flash attention, fp16 MFMA, fixed-offset softmax ----------
// qkh: [8192,1024] f16, cols [h*64+d]=q, [512+h*64+d]=k
// vt:  [(b*8+h)*64+d][1024] f16 (V transposed per head)
// ao:  [8192,512] f16, b n (h d)
// 512 threads = 8 waves; block covers 128 q-rows; KV tile 64 tokens.
#define QSC 0.18033688f   // 0.125 * log2(e)
#define MOFF 5.7707801f   // 4 * log2(e)

__global__ __launch_bounds__(512) void flash16_kernel(
    const _Float16* __restrict__ qkh, const _Float16* __restrict__ vt,
    _Float16* __restrict__ ao) {
  __shared__ char smem[32768];   // Ks 8K | Vt 8K | P 8x2K
  const int qt = blockIdx.x;     // 0..7 (128 q-rows each)
  const int bh = blockIdx.y;     // 0..63
  const int b = bh >> 3, h = bh & 7;
  const int tid = threadIdx.x;
  const int wv = tid >> 6, lane = tid & 63;
  const int l15 = lane & 15, g = lane >> 4;
  const int swz = (l15 & 7) << 4;
  const int qrow0 = b * SEQ + qt * 128;

  // Q fragments (B operand), pre-scaled by 0.125*log2e
  half8 qf[2];
  {
    const _Float16* qp = qkh + (size_t)(qrow0 + wv * 16 + l15) * 1024 + h * DH;
    qf[0] = *(const half8*)(qp + g * 8);
    qf[1] = *(const half8*)(qp + g * 8 + 32);
    qf[0] *= (_Float16)QSC;
    qf[1] *= (_Float16)QSC;
  }

  float lsum = 0.f;
  floatx4 oacc[4] = {};

  const int lrow = lane >> 3;          // 0..7
  const int lchk = (lane & 7) * 16;
  const int ssw = lchk ^ (lrow << 4);  // pre-swizzled source offset
  const _Float16* kbase = qkh + 512 + h * DH;
  const _Float16* vbase = vt + (size_t)bh * 64 * 1024;
  char* pb = smem + 16384 + wv * 2048 + l15 * 128;   // per-wave P strip

  for (int kt = 0; kt < 16; ++kt) {
    const int krow = b * SEQ + kt * 64 + wv * 8 + lrow;
    gll16((const char*)(kbase + (size_t)krow * 1024) + ssw, smem + wv * 1024);
    gll16((const char*)(vbase + (size_t)(wv * 8 + lrow) * 1024 + kt * 64) + ssw,
          smem + 8192 + wv * 1024);
    __syncthreads();   // K/V resident

    // S2^T[k][q] = mfma(A=K, B=Qscaled)  (log2-domain scores)
    floatx4 sacc[4] = {};
    #pragma unroll
    for (int kk = 0; kk < 2; ++kk) {
      #pragma unroll
      for (int mt = 0; mt < 4; ++mt) {
        half8 af = *(const half8*)(smem + (16 * mt + l15) * 128 +
                                   ((g * 16 + kk * 64) ^ swz));
        sacc[mt] = __builtin_amdgcn_mfma_f32_16x16x32_f16(af, qf[kk], sacc[mt], 0, 0, 0);
      }
    }

    // fixed-offset softmax: p = 2^(s2 - MOFF); 1/lsum cancels the offset
    float rs = 0.f;
    #pragma unroll
    for (int mt = 0; mt < 4; ++mt) {
      float p0 = exp2f(sacc[mt][0] - MOFF);
      float p1 = exp2f(sacc[mt][1] - MOFF);
      float p2 = exp2f(sacc[mt][2] - MOFF);
      float p3 = exp2f(sacc[mt][3] - MOFF);
      rs += (p0 + p1) + (p2 + p3);
      half4v pv;
      pv[0] = (_Float16)p0; pv[1] = (_Float16)p1;
      pv[2] = (_Float16)p2; pv[3] = (_Float16)p3;
      *(half4v*)(pb + ((32 * mt + 8 * g) ^ swz)) = pv;
    }
    rs += __shfl_xor(rs, 16);
    rs += __shfl_xor(rs, 32);
    lsum += rs;

    // O^T[d][q] += mfma(A=Vt, B=P^T)
    #pragma unroll
    for (int kk = 0; kk < 2; ++kk) {
      half8 pf = *(const half8*)(pb + ((g * 16 + kk * 64) ^ swz));
      #pragma unroll
      for (int mt = 0; mt < 4; ++mt) {
        half8 vf = *(const half8*)(smem + 8192 + (16 * mt + l15) * 128 +
                                   ((g * 16 + kk * 64) ^ swz));
        oacc[mt] = __builtin_amdgcn_mfma_f32_16x16x32_f16(vf, pf, oacc[mt], 0, 0, 0);
      }
    }
    __syncthreads();   // MFMA reads done before next tile's gll overwrites
  }

  const float inv = 1.0f / lsum;
  _Float16* op = ao + (size_t)(qrow0 + wv * 16 + l15) * 512 + h * DH;
  #pragma unroll
  for (int mt = 0; mt < 4; ++mt) {
    half4v hv;
    hv[0] = (_Float16)(oacc[mt][0] * inv);
    hv[1] = (_Float16)(oacc[mt][1] * inv);
    hv[2] = (_Float16)(oacc[mt][2] * inv);
    hv[3] = (_Float16)(oacc[mt][3] * inv);
    *(half4v*)(op + 16 * mt + 4 * g) = hv;
  }
}

extern "C" void kernel_launch(void* const* d_in, const int* in_sizes, int n_in,
                              void* d_out, int out_size, void* d_ws, size_t ws_size,
                              hipStream_t stream) {
  const float* x     = (const float*)d_in[0];
  const float* gamma = (const float*)d_in[1];
  const float* beta  = (const float*)d_in[2];
  const float* W_qk  = (const float*)d_in[3];
  const float* W_v   = (const float*)d_in[4];
  const float* W_out = (const float*)d_in[5];
  float* out = (float*)d_out;
  char* ws = (char*)d_ws;

  const size_t MB = 1024 * 1024;
  _Float16* xn16  = (_Float16*)ws;                    //  8 MiB [8192,512]
  _Float16* qkh   = (_Float16*)(ws + 8 * MB);         // 16 MiB [8192,1024]
  _Float16* vt    = (_Float16*)(ws + 24 * MB);        //  8 MiB per-head V^T
  _Float16* ao16  = (_Float16*)(ws + 32 * MB);        //  8 MiB [8192,512]
  _Float16* WqkT  = (_Float16*)(ws + 40 * MB);        //  1 MiB [1024,512]
  _Float16* WvT   = (_Float16*)(ws + 41 * MB);        // .5 MiB [512,512]
  _Float16* WoutT = (_Float16*)(ws + 41 * MB + 512 * 1024); // .5 MiB [512,512]

  transpose_cvt_kernel<<<dim3(32, 16), 256, 0, stream>>>(W_qk, WqkT, 512, 1024);
  transpose_cvt_kernel<<<dim3(16, 16), 256, 0, stream>>>(W_v, WvT, 512, 512);
  transpose_cvt_kernel<<<dim3(16, 16), 256, 0, stream>>>(W_out, WoutT, 512, 512);
  ln_kernel<<<TOK / 4, 256, 0, stream>>>(x, gamma, beta, xn16);
  hgemm_kernel<1><<<dim3(8, 64), 256, 0, stream>>>(xn16, WqkT, qkh, TOK, 1024, 512);
  hgemm_kernel<2><<<dim3(4, 64), 256, 0, stream>>>(xn16, WvT, vt, TOK, 512, 512);
  flash16_kernel<<<dim3(8, 64), 512, 0, stream>>>(qkh, vt, ao16);
  hgemm_kernel<0><<<dim3(4, 64), 256, 0, stream>>>(ao16, WoutT, out, TOK, 512, 512);
}

// Round 5
// 87.973 us; speedup vs baseline: 8.0758x; 1.1420x over previous
//
#include <hip/hip_runtime.h>

#define TOK 8192       // B*N rows
#define DMODEL 512
#define SEQ 1024
#define NH 8
#define DH 64

typedef _Float16 half8 __attribute__((ext_vector_type(8)));
typedef _Float16 half4v __attribute__((ext_vector_type(4)));
typedef float floatx4 __attribute__((ext_vector_type(4)));

__device__ __forceinline__ void gll16(const void* g, void* l) {
  __builtin_amdgcn_global_load_lds(
      (const __attribute__((address_space(1))) void*)g,
      (__attribute__((address_space(3))) void*)l, 16, 0, 0);
}

// ---------------- LayerNorm: one wave per row, f16 output ----------------
__global__ __launch_bounds__(256) void ln_kernel(
    const float* __restrict__ x, const float* __restrict__ gamma,
    const float* __restrict__ beta, _Float16* __restrict__ xn) {
  const int row = blockIdx.x * 4 + (threadIdx.x >> 6);
  const int t = threadIdx.x & 63;
  const float* xr = x + (size_t)row * DMODEL;
  const float4 a = *(const float4*)(xr + t * 4);
  const float4 b = *(const float4*)(xr + 256 + t * 4);
  float s  = a.x + a.y + a.z + a.w + b.x + b.y + b.z + b.w;
  float ss = a.x*a.x + a.y*a.y + a.z*a.z + a.w*a.w
           + b.x*b.x + b.y*b.y + b.z*b.z + b.w*b.w;
  #pragma unroll
  for (int m = 1; m < 64; m <<= 1) {
    s  += __shfl_xor(s, m);
    ss += __shfl_xor(ss, m);
  }
  const float mean = s * (1.0f / DMODEL);
  const float var  = ss * (1.0f / DMODEL) - mean * mean;
  const float inv  = rsqrtf(var + 1e-5f);
  const float4 g0  = *(const float4*)(gamma + t * 4);
  const float4 g1  = *(const float4*)(gamma + 256 + t * 4);
  const float4 be0 = *(const float4*)(beta + t * 4);
  const float4 be1 = *(const float4*)(beta + 256 + t * 4);
  half4v o0, o1;
  o0[0] = (_Float16)((a.x - mean) * inv * g0.x + be0.x);
  o0[1] = (_Float16)((a.y - mean) * inv * g0.y + be0.y);
  o0[2] = (_Float16)((a.z - mean) * inv * g0.z + be0.z);
  o0[3] = (_Float16)((a.w - mean) * inv * g0.w + be0.w);
  o1[0] = (_Float16)((b.x - mean) * inv * g1.x + be1.x);
  o1[1] = (_Float16)((b.y - mean) * inv * g1.y + be1.y);
  o1[2] = (_Float16)((b.z - mean) * inv * g1.z + be1.z);
  o1[3] = (_Float16)((b.w - mean) * inv * g1.w + be1.w);
  _Float16* outr = xn + (size_t)row * DMODEL;
  *(half4v*)(outr + t * 4) = o0;
  *(half4v*)(outr + 256 + t * 4) = o1;
}

// ---------------- W[K][N] fp32 -> WT[N][K] f16 ----------------
__global__ __launch_bounds__(256) void transpose_cvt_kernel(
    const float* __restrict__ W, _Float16* __restrict__ WT, int K, int N) {
  __shared__ float t[32][33];
  const int tx = threadIdx.x & 31, ty = threadIdx.x >> 5;
  const int n0 = blockIdx.x * 32, k0 = blockIdx.y * 32;
  #pragma unroll
  for (int j = 0; j < 4; ++j)
    t[ty + j * 8][tx] = W[(size_t)(k0 + ty + j * 8) * N + n0 + tx];
  __syncthreads();
  #pragma unroll
  for (int j = 0; j < 4; ++j)
    WT[(size_t)(n0 + ty + j * 8) * K + k0 + tx] = (_Float16)t[tx][ty + j * 8];
}

// ---------------- f16 MFMA GEMM: C[M,N] = A[M,K] * Bt[N,K]^T ----------------
// 2-phase pipelined global_load_lds staging, double-buffered LDS.
// Grid: blockIdx.x = bm (XCD-locality on A panel), blockIdx.y = bn.
// MODE 0: fp32 C[M,N]   MODE 1: f16 C[M,N]
// MODE 2: f16 vt store: vt[((tok>>10)*8 + col>>6)*64 + (col&63)][tok&1023]
template <int MODE>
__global__ __launch_bounds__(256) void hgemm_kernel(
    const _Float16* __restrict__ A, const _Float16* __restrict__ Bt,
    void* __restrict__ Cout, int M, int N, int K) {
  __shared__ char smem[65536];  // 2 stages x (As 16K | Bs 16K)
  const int tid = threadIdx.x;
  const int bm = blockIdx.x, bn = blockIdx.y;
  const int wv = tid >> 6, lane = tid & 63;
  const int l15 = lane & 15, g = lane >> 4;
  const int wr = wv >> 1, wc = wv & 1;
  const int swz = (l15 & 7) << 4;
  const _Float16* Ab = A + (size_t)(bm * 128) * K;
  const _Float16* Bb = Bt + (size_t)(bn * 128) * K;
  const int lrow = lane >> 3;          // 0..7
  const int lchk = (lane & 7) * 16;    // byte chunk
  const int ssw = lchk ^ (lrow << 4);  // pre-swizzled source byte offset

  #define HG_STAGE(buf, kt)                                                  \
    _Pragma("unroll")                                                        \
    for (int i = 0; i < 4; ++i) {                                            \
      const int row = wv * 32 + i * 8 + lrow;                                \
      gll16((const char*)(Ab + (size_t)row * K + (kt)) + ssw,                \
            smem + (buf) * 32768 + (wv * 32 + i * 8) * 128);                 \
      gll16((const char*)(Bb + (size_t)row * K + (kt)) + ssw,                \
            smem + (buf) * 32768 + 16384 + (wv * 32 + i * 8) * 128);         \
    }

  floatx4 acc[4][4] = {};
  HG_STAGE(0, 0);
  __syncthreads();               // vmcnt(0) drain + barrier: stage 0 resident
  int cur = 0;
  for (int kt = 0; kt < K; kt += 64) {
    if (kt + 64 < K) { HG_STAGE(cur ^ 1, kt + 64); }  // prefetch next tile
    const char* sb = smem + cur * 32768;
    #pragma unroll
    for (int kk = 0; kk < 2; ++kk) {
      half8 af[4], bf[4];
      #pragma unroll
      for (int mt = 0; mt < 4; ++mt)
        af[mt] = *(const half8*)(sb + (wr * 64 + mt * 16 + l15) * 128 +
                                 ((g * 16 + kk * 64) ^ swz));
      #pragma unroll
      for (int nt = 0; nt < 4; ++nt)
        bf[nt] = *(const half8*)(sb + 16384 + (wc * 64 + nt * 16 + l15) * 128 +
                                 ((g * 16 + kk * 64) ^ swz));
      #pragma unroll
      for (int mt = 0; mt < 4; ++mt)
        #pragma unroll
        for (int nt = 0; nt < 4; ++nt)
          acc[mt][nt] = __builtin_amdgcn_mfma_f32_16x16x32_f16(
              af[mt], bf[nt], acc[mt][nt], 0, 0, 0);
    }
    __syncthreads();             // prefetch landed; reads of cur done
    cur ^= 1;
  }
  #undef HG_STAGE
  const int m0 = bm * 128 + wr * 64;
  const int n0 = bn * 128 + wc * 64;
  if constexpr (MODE == 0) {
    float* C = (float*)Cout;
    #pragma unroll
    for (int mt = 0; mt < 4; ++mt)
      #pragma unroll
      for (int nt = 0; nt < 4; ++nt) {
        const int n = n0 + nt * 16 + l15;
        #pragma unroll
        for (int r = 0; r < 4; ++r)
          C[(size_t)(m0 + mt * 16 + 4 * g + r) * N + n] = acc[mt][nt][r];
      }
  } else if constexpr (MODE == 1) {
    _Float16* C = (_Float16*)Cout;
    #pragma unroll
    for (int mt = 0; mt < 4; ++mt)
      #pragma unroll
      for (int nt = 0; nt < 4; ++nt) {
        const int n = n0 + nt * 16 + l15;
        #pragma unroll
        for (int r = 0; r < 4; ++r)
          C[(size_t)(m0 + mt * 16 + 4 * g + r) * N + n] = (_Float16)acc[mt][nt][r];
      }
  } else {
    _Float16* C = (_Float16*)Cout;
    #pragma unroll
    for (int mt = 0; mt < 4; ++mt) {
      const int mrow = m0 + mt * 16 + 4 * g;   // 4-aligned token
      const int b = mrow >> 10, tok = mrow & 1023;
      #pragma unroll
      for (int nt = 0; nt < 4; ++nt) {
        const int col = n0 + nt * 16 + l15;
        half4v hv;
        #pragma unroll
        for (int r = 0; r < 4; ++r) hv[r] = (_Float16)acc[mt][nt][r];
        *(half4v*)(C + ((size_t)((b * 8 + (col >> 6)) * 64 + (col & 63)) << 10) + tok) = hv;
      }
    }
  }
}

// ---------------- flash attention, fp16 MFMA, fixed-offset softmax ----------
// 2-phase pipelined K/V staging, double-buffered. blockIdx.x = bh (XCD-local KV).
// qkh: [8192,1024] f16; vt: [(b*8+h)*64+d][1024] f16; ao: [8192,512] f16
#define QSC 0.18033688f   // 0.125 * log2(e)
#define MOFF 5.7707801f   // 4 * log2(e)

__global__ __launch_bounds__(512) void flash16_kernel(
    const _Float16* __restrict__ qkh, const _Float16* __restrict__ vt,
    _Float16* __restrict__ ao) {
  __shared__ char smem[49152];   // 2 x (K 8K | V 8K) | P 8x2K
  const int bh = blockIdx.x;     // 0..63  (fastest -> same-bh blocks share XCD)
  const int qt = blockIdx.y;     // 0..7   (128 q-rows each)
  const int b = bh >> 3, h = bh & 7;
  const int tid = threadIdx.x;
  const int wv = tid >> 6, lane = tid & 63;
  const int l15 = lane & 15, g = lane >> 4;
  const int swz = (l15 & 7) << 4;
  const int qrow0 = b * SEQ + qt * 128;

  // Q fragments (B operand), pre-scaled by 0.125*log2e
  half8 qf[2];
  {
    const _Float16* qp = qkh + (size_t)(qrow0 + wv * 16 + l15) * 1024 + h * DH;
    qf[0] = *(const half8*)(qp + g * 8);
    qf[1] = *(const half8*)(qp + g * 8 + 32);
    qf[0] *= (_Float16)QSC;
    qf[1] *= (_Float16)QSC;
  }

  float lsum = 0.f;
  floatx4 oacc[4] = {};

  const int lrow = lane >> 3;          // 0..7
  const int lchk = (lane & 7) * 16;
  const int ssw = lchk ^ (lrow << 4);  // pre-swizzled source offset
  const _Float16* kbase = qkh + 512 + h * DH;
  const _Float16* vbase = vt + (size_t)bh * 64 * 1024;
  char* pb = smem + 32768 + wv * 2048 + l15 * 128;   // per-wave P strip

  #define FL_STAGE(buf, kt)                                                   \
    {                                                                         \
      const int krow = b * SEQ + (kt) * 64 + wv * 8 + lrow;                   \
      gll16((const char*)(kbase + (size_t)krow * 1024) + ssw,                 \
            smem + (buf) * 16384 + wv * 1024);                                \
      gll16((const char*)(vbase + (size_t)(wv * 8 + lrow) * 1024 +            \
                          (kt) * 64) + ssw,                                   \
            smem + (buf) * 16384 + 8192 + wv * 1024);                         \
    }

  FL_STAGE(0, 0);
  __syncthreads();               // stage 0 resident
  int cur = 0;
  for (int kt = 0; kt < 16; ++kt) {
    if (kt < 15) FL_STAGE(cur ^ 1, kt + 1);   // prefetch next K/V tile
    const char* sb = smem + cur * 16384;

    // S2^T[k][q] = mfma(A=K, B=Qscaled)  (log2-domain scores)
    floatx4 sacc[4] = {};
    #pragma unroll
    for (int kk = 0; kk < 2; ++kk) {
      #pragma unroll
      for (int mt = 0; mt < 4; ++mt) {
        half8 af = *(const half8*)(sb + (16 * mt + l15) * 128 +
                                   ((g * 16 + kk * 64) ^ swz));
        sacc[mt] = __builtin_amdgcn_mfma_f32_16x16x32_f16(af, qf[kk], sacc[mt], 0, 0, 0);
      }
    }

    // fixed-offset softmax: p = 2^(s2 - MOFF); 1/lsum cancels the offset
    float rs = 0.f;
    #pragma unroll
    for (int mt = 0; mt < 4; ++mt) {
      float p0 = exp2f(sacc[mt][0] - MOFF);
      float p1 = exp2f(sacc[mt][1] - MOFF);
      float p2 = exp2f(sacc[mt][2] - MOFF);
      float p3 = exp2f(sacc[mt][3] - MOFF);
      rs += (p0 + p1) + (p2 + p3);
      half4v pv;
      pv[0] = (_Float16)p0; pv[1] = (_Float16)p1;
      pv[2] = (_Float16)p2; pv[3] = (_Float16)p3;
      *(half4v*)(pb + ((32 * mt + 8 * g) ^ swz)) = pv;
    }
    rs += __shfl_xor(rs, 16);
    rs += __shfl_xor(rs, 32);
    lsum += rs;

    // O^T[d][q] += mfma(A=Vt, B=P^T)
    #pragma unroll
    for (int kk = 0; kk < 2; ++kk) {
      half8 pf = *(const half8*)(pb + ((g * 16 + kk * 64) ^ swz));
      #pragma unroll
      for (int mt = 0; mt < 4; ++mt) {
        half8 vf = *(const half8*)(sb + 8192 + (16 * mt + l15) * 128 +
                                   ((g * 16 + kk * 64) ^ swz));
        oacc[mt] = __builtin_amdgcn_mfma_f32_16x16x32_f16(vf, pf, oacc[mt], 0, 0, 0);
      }
    }
    __syncthreads();   // prefetch landed; reads of cur done
    cur ^= 1;
  }
  #undef FL_STAGE

  const float inv = 1.0f / lsum;
  _Float16* op = ao + (size_t)(qrow0 + wv * 16 + l15) * 512 + h * DH;
  #pragma unroll
  for (int mt = 0; mt < 4; ++mt) {
    half4v hv;
    hv[0] = (_Float16)(oacc[mt][0] * inv);
    hv[1] = (_Float16)(oacc[mt][1] * inv);
    hv[2] = (_Float16)(oacc[mt][2] * inv);
    hv[3] = (_Float16)(oacc[mt][3] * inv);
    *(half4v*)(op + 16 * mt + 4 * g) = hv;
  }
}

extern "C" void kernel_launch(void* const* d_in, const int* in_sizes, int n_in,
                              void* d_out, int out_size, void* d_ws, size_t ws_size,
                              hipStream_t stream) {
  const float* x     = (const float*)d_in[0];
  const float* gamma = (const float*)d_in[1];
  const float* beta  = (const float*)d_in[2];
  const float* W_qk  = (const float*)d_in[3];
  const float* W_v   = (const float*)d_in[4];
  const float* W_out = (const float*)d_in[5];
  float* out = (float*)d_out;
  char* ws = (char*)d_ws;

  const size_t MB = 1024 * 1024;
  _Float16* xn16  = (_Float16*)ws;                    //  8 MiB [8192,512]
  _Float16* qkh   = (_Float16*)(ws + 8 * MB);         // 16 MiB [8192,1024]
  _Float16* vt    = (_Float16*)(ws + 24 * MB);        //  8 MiB per-head V^T
  _Float16* ao16  = (_Float16*)(ws + 32 * MB);        //  8 MiB [8192,512]
  _Float16* WqkT  = (_Float16*)(ws + 40 * MB);        //  1 MiB [1024,512]
  _Float16* WvT   = (_Float16*)(ws + 41 * MB);        // .5 MiB [512,512]
  _Float16* WoutT = (_Float16*)(ws + 41 * MB + 512 * 1024); // .5 MiB [512,512]

  transpose_cvt_kernel<<<dim3(32, 16), 256, 0, stream>>>(W_qk, WqkT, 512, 1024);
  transpose_cvt_kernel<<<dim3(16, 16), 256, 0, stream>>>(W_v, WvT, 512, 512);
  transpose_cvt_kernel<<<dim3(16, 16), 256, 0, stream>>>(W_out, WoutT, 512, 512);
  ln_kernel<<<TOK / 4, 256, 0, stream>>>(x, gamma, beta, xn16);
  hgemm_kernel<1><<<dim3(64, 8), 256, 0, stream>>>(xn16, WqkT, qkh, TOK, 1024, 512);
  hgemm_kernel<2><<<dim3(64, 4), 256, 0, stream>>>(xn16, WvT, vt, TOK, 512, 512);
  flash16_kernel<<<dim3(64, 8), 512, 0, stream>>>(qkh, vt, ao16);
  hgemm_kernel<0><<<dim3(64, 4), 256, 0, stream>>>(ao16, WoutT, out, TOK, 512, 512);
}

// Round 6
// 81.897 us; speedup vs baseline: 8.6749x; 1.0742x over previous
//
#include <hip/hip_runtime.h>

#define TOK 8192       // B*N rows
#define DMODEL 512
#define SEQ 1024
#define NH 8
#define DH 64

typedef _Float16 half8 __attribute__((ext_vector_type(8)));
typedef _Float16 half4v __attribute__((ext_vector_type(4)));
typedef float floatx4 __attribute__((ext_vector_type(4)));

__device__ __forceinline__ void gll16(const void* g, void* l) {
  __builtin_amdgcn_global_load_lds(
      (const __attribute__((address_space(1))) void*)g,
      (__attribute__((address_space(3))) void*)l, 16, 0, 0);
}

// ---------------- LayerNorm: one wave per row, f16 output ----------------
__global__ __launch_bounds__(256) void ln_kernel(
    const float* __restrict__ x, const float* __restrict__ gamma,
    const float* __restrict__ beta, _Float16* __restrict__ xn) {
  const int row = blockIdx.x * 4 + (threadIdx.x >> 6);
  const int t = threadIdx.x & 63;
  const float* xr = x + (size_t)row * DMODEL;
  const float4 a = *(const float4*)(xr + t * 4);
  const float4 b = *(const float4*)(xr + 256 + t * 4);
  float s  = a.x + a.y + a.z + a.w + b.x + b.y + b.z + b.w;
  float ss = a.x*a.x + a.y*a.y + a.z*a.z + a.w*a.w
           + b.x*b.x + b.y*b.y + b.z*b.z + b.w*b.w;
  #pragma unroll
  for (int m = 1; m < 64; m <<= 1) {
    s  += __shfl_xor(s, m);
    ss += __shfl_xor(ss, m);
  }
  const float mean = s * (1.0f / DMODEL);
  const float var  = ss * (1.0f / DMODEL) - mean * mean;
  const float inv  = rsqrtf(var + 1e-5f);
  const float4 g0  = *(const float4*)(gamma + t * 4);
  const float4 g1  = *(const float4*)(gamma + 256 + t * 4);
  const float4 be0 = *(const float4*)(beta + t * 4);
  const float4 be1 = *(const float4*)(beta + 256 + t * 4);
  half4v o0, o1;
  o0[0] = (_Float16)((a.x - mean) * inv * g0.x + be0.x);
  o0[1] = (_Float16)((a.y - mean) * inv * g0.y + be0.y);
  o0[2] = (_Float16)((a.z - mean) * inv * g0.z + be0.z);
  o0[3] = (_Float16)((a.w - mean) * inv * g0.w + be0.w);
  o1[0] = (_Float16)((b.x - mean) * inv * g1.x + be1.x);
  o1[1] = (_Float16)((b.y - mean) * inv * g1.y + be1.y);
  o1[2] = (_Float16)((b.z - mean) * inv * g1.z + be1.z);
  o1[3] = (_Float16)((b.w - mean) * inv * g1.w + be1.w);
  _Float16* outr = xn + (size_t)row * DMODEL;
  *(half4v*)(outr + t * 4) = o0;
  *(half4v*)(outr + 256 + t * 4) = o1;
}

// -------- all 3 weight transposes in one launch: W[K][N] f32 -> WT[N][K] f16
// z=0: W_qk (N=1024) -> WqkvT rows 0..1023
// z=1: W_v  (N=512)  -> WqkvT rows 1024..1535
// z=2: W_out(N=512)  -> WoutT rows 0..511
__global__ __launch_bounds__(256) void transpose_cvt3_kernel(
    const float* __restrict__ Wqk, const float* __restrict__ Wv,
    const float* __restrict__ Wo, _Float16* __restrict__ WqkvT,
    _Float16* __restrict__ WoutT) {
  const int z = blockIdx.z;
  const float* W;
  _Float16* dst;
  int N, rowoff;
  if (z == 0)      { W = Wqk; dst = WqkvT; N = 1024; rowoff = 0; }
  else if (z == 1) { W = Wv;  dst = WqkvT; N = 512;  rowoff = 1024; }
  else             { W = Wo;  dst = WoutT; N = 512;  rowoff = 0; }
  const int n0 = blockIdx.x * 32;
  if (n0 >= N) return;
  const int k0 = blockIdx.y * 32;
  __shared__ float t[32][33];
  const int tx = threadIdx.x & 31, ty = threadIdx.x >> 5;
  #pragma unroll
  for (int j = 0; j < 4; ++j)
    t[ty + j * 8][tx] = W[(size_t)(k0 + ty + j * 8) * N + n0 + tx];
  __syncthreads();
  #pragma unroll
  for (int j = 0; j < 4; ++j)
    dst[(size_t)(rowoff + n0 + ty + j * 8) * 512 + k0 + tx] =
        (_Float16)t[tx][ty + j * 8];
}

// ---------------- f16 MFMA GEMM: C = A[M,K] * Bt[N,K]^T ----------------
// 2-phase pipelined global_load_lds staging, double-buffered LDS.
// blockIdx.x = bm (XCD locality on A panel), blockIdx.y = bn.
// MODE 0: fp32 C[M,512]
// MODE 3: fused QKV epilogue: n<1024 -> qkh[M,1024]; n>=1024 -> vt transposed
template <int MODE>
__global__ __launch_bounds__(256) void hgemm_kernel(
    const _Float16* __restrict__ A, const _Float16* __restrict__ Bt,
    void* __restrict__ Cout, void* __restrict__ Cout2, int M, int N, int K) {
  __shared__ char smem[65536];  // 2 stages x (As 16K | Bs 16K)
  const int tid = threadIdx.x;
  const int bm = blockIdx.x, bn = blockIdx.y;
  const int wv = tid >> 6, lane = tid & 63;
  const int l15 = lane & 15, g = lane >> 4;
  const int wr = wv >> 1, wc = wv & 1;
  const int swz = (l15 & 7) << 4;
  const _Float16* Ab = A + (size_t)(bm * 128) * K;
  const _Float16* Bb = Bt + (size_t)(bn * 128) * K;
  const int lrow = lane >> 3;          // 0..7
  const int lchk = (lane & 7) * 16;    // byte chunk
  const int ssw = lchk ^ (lrow << 4);  // pre-swizzled source byte offset

  #define HG_STAGE(buf, kt)                                                  \
    _Pragma("unroll")                                                        \
    for (int i = 0; i < 4; ++i) {                                            \
      const int row = wv * 32 + i * 8 + lrow;                                \
      gll16((const char*)(Ab + (size_t)row * K + (kt)) + ssw,                \
            smem + (buf) * 32768 + (wv * 32 + i * 8) * 128);                 \
      gll16((const char*)(Bb + (size_t)row * K + (kt)) + ssw,                \
            smem + (buf) * 32768 + 16384 + (wv * 32 + i * 8) * 128);         \
    }

  floatx4 acc[4][4] = {};
  HG_STAGE(0, 0);
  __syncthreads();
  int cur = 0;
  for (int kt = 0; kt < K; kt += 64) {
    if (kt + 64 < K) { HG_STAGE(cur ^ 1, kt + 64); }
    const char* sb = smem + cur * 32768;
    #pragma unroll
    for (int kk = 0; kk < 2; ++kk) {
      half8 af[4], bf[4];
      #pragma unroll
      for (int mt = 0; mt < 4; ++mt)
        af[mt] = *(const half8*)(sb + (wr * 64 + mt * 16 + l15) * 128 +
                                 ((g * 16 + kk * 64) ^ swz));
      #pragma unroll
      for (int nt = 0; nt < 4; ++nt)
        bf[nt] = *(const half8*)(sb + 16384 + (wc * 64 + nt * 16 + l15) * 128 +
                                 ((g * 16 + kk * 64) ^ swz));
      #pragma unroll
      for (int mt = 0; mt < 4; ++mt)
        #pragma unroll
        for (int nt = 0; nt < 4; ++nt)
          acc[mt][nt] = __builtin_amdgcn_mfma_f32_16x16x32_f16(
              af[mt], bf[nt], acc[mt][nt], 0, 0, 0);
    }
    __syncthreads();
    cur ^= 1;
  }
  #undef HG_STAGE
  const int m0 = bm * 128 + wr * 64;
  const int n0 = bn * 128 + wc * 64;
  if constexpr (MODE == 0) {
    float* C = (float*)Cout;
    #pragma unroll
    for (int mt = 0; mt < 4; ++mt)
      #pragma unroll
      for (int nt = 0; nt < 4; ++nt) {
        const int n = n0 + nt * 16 + l15;
        #pragma unroll
        for (int r = 0; r < 4; ++r)
          C[(size_t)(m0 + mt * 16 + 4 * g + r) * 512 + n] = acc[mt][nt][r];
      }
  } else {
    _Float16* Q = (_Float16*)Cout;   // qkh [M,1024]
    _Float16* V = (_Float16*)Cout2;  // vt  per-head transposed
    #pragma unroll
    for (int mt = 0; mt < 4; ++mt) {
      const int mrow = m0 + mt * 16 + 4 * g;
      const int b = mrow >> 10, tok = mrow & 1023;
      #pragma unroll
      for (int nt = 0; nt < 4; ++nt) {
        const int n = n0 + nt * 16 + l15;   // uniform side per (bn,wc,nt)
        if (n < 1024) {
          #pragma unroll
          for (int r = 0; r < 4; ++r)
            Q[(size_t)(mrow + r) * 1024 + n] = (_Float16)acc[mt][nt][r];
        } else {
          const int cv = n - 1024;
          half4v hv;
          #pragma unroll
          for (int r = 0; r < 4; ++r) hv[r] = (_Float16)acc[mt][nt][r];
          *(half4v*)(V + ((size_t)((b * 8 + (cv >> 6)) * 64 + (cv & 63)) << 10) + tok) = hv;
        }
      }
    }
  }
}

// ---------------- flash attention, fp16 MFMA, fixed-offset softmax ----------
// NBUF=3 pipeline, counted vmcnt + raw s_barrier (prefetch distance 2).
// blockIdx.x = bh (XCD-local KV). qkh: [8192,1024]; vt per-head T; ao f16.
#define QSC 0.18033688f   // 0.125 * log2(e)
#define MOFF 5.7707801f   // 4 * log2(e)

__global__ __launch_bounds__(512) void flash16_kernel(
    const _Float16* __restrict__ qkh, const _Float16* __restrict__ vt,
    _Float16* __restrict__ ao) {
  __shared__ char smem[65536];   // 3 x (K 8K | V 8K) | P 8x2K @49152
  const int bh = blockIdx.x;     // 0..63
  const int qt = blockIdx.y;     // 0..7
  const int b = bh >> 3, h = bh & 7;
  const int tid = threadIdx.x;
  const int wv = tid >> 6, lane = tid & 63;
  const int l15 = lane & 15, g = lane >> 4;
  const int swz = (l15 & 7) << 4;
  const int qrow0 = b * SEQ + qt * 128;

  half8 qf[2];
  {
    const _Float16* qp = qkh + (size_t)(qrow0 + wv * 16 + l15) * 1024 + h * DH;
    qf[0] = *(const half8*)(qp + g * 8);
    qf[1] = *(const half8*)(qp + g * 8 + 32);
    qf[0] *= (_Float16)QSC;
    qf[1] *= (_Float16)QSC;
  }

  float lsum = 0.f;
  floatx4 oacc[4] = {};

  const int lrow = lane >> 3;
  const int lchk = (lane & 7) * 16;
  const int ssw = lchk ^ (lrow << 4);
  const _Float16* kbase = qkh + 512 + h * DH;
  const _Float16* vbase = vt + (size_t)bh * 64 * 1024;
  char* pb = smem + 49152 + wv * 2048 + l15 * 128;   // per-wave P strip

  #define FL_STAGE(buf, kt)                                                   \
    {                                                                         \
      const int krow = b * SEQ + (kt) * 64 + wv * 8 + lrow;                   \
      gll16((const char*)(kbase + (size_t)krow * 1024) + ssw,                 \
            smem + (buf) * 16384 + wv * 1024);                                \
      gll16((const char*)(vbase + (size_t)(wv * 8 + lrow) * 1024 +            \
                          (kt) * 64) + ssw,                                   \
            smem + (buf) * 16384 + 8192 + wv * 1024);                         \
    }

  FL_STAGE(0, 0);
  FL_STAGE(1, 1);
  int cur = 0;
  for (int kt = 0; kt < 16; ++kt) {
    // own stage(kt) complete (2 newest outstanding = stage kt+1); all-wave via barrier
    if (kt < 15) asm volatile("s_waitcnt vmcnt(2)" ::: "memory");
    else         asm volatile("s_waitcnt vmcnt(0)" ::: "memory");
    __builtin_amdgcn_s_barrier();
    asm volatile("" ::: "memory");
    const int nxt = cur + 2 >= 3 ? cur - 1 : cur + 2;
    if (kt + 2 < 16) FL_STAGE(nxt, kt + 2);   // overwrites buf of tile kt-1 (all waves done)
    const char* sb = smem + cur * 16384;

    // S2^T[k][q] = mfma(A=K, B=Qscaled)
    floatx4 sacc[4] = {};
    __builtin_amdgcn_s_setprio(1);
    #pragma unroll
    for (int kk = 0; kk < 2; ++kk) {
      #pragma unroll
      for (int mt = 0; mt < 4; ++mt) {
        half8 af = *(const half8*)(sb + (16 * mt + l15) * 128 +
                                   ((g * 16 + kk * 64) ^ swz));
        sacc[mt] = __builtin_amdgcn_mfma_f32_16x16x32_f16(af, qf[kk], sacc[mt], 0, 0, 0);
      }
    }
    __builtin_amdgcn_s_setprio(0);

    // fixed-offset softmax: p = 2^(s2 - MOFF); 1/lsum cancels the offset
    float rs = 0.f;
    #pragma unroll
    for (int mt = 0; mt < 4; ++mt) {
      float p0 = exp2f(sacc[mt][0] - MOFF);
      float p1 = exp2f(sacc[mt][1] - MOFF);
      float p2 = exp2f(sacc[mt][2] - MOFF);
      float p3 = exp2f(sacc[mt][3] - MOFF);
      rs += (p0 + p1) + (p2 + p3);
      half4v pv;
      pv[0] = (_Float16)p0; pv[1] = (_Float16)p1;
      pv[2] = (_Float16)p2; pv[3] = (_Float16)p3;
      *(half4v*)(pb + ((32 * mt + 8 * g) ^ swz)) = pv;
    }
    rs += __shfl_xor(rs, 16);
    rs += __shfl_xor(rs, 32);
    lsum += rs;

    // O^T[d][q] += mfma(A=Vt, B=P^T)
    __builtin_amdgcn_s_setprio(1);
    #pragma unroll
    for (int kk = 0; kk < 2; ++kk) {
      half8 pf = *(const half8*)(pb + ((g * 16 + kk * 64) ^ swz));
      #pragma unroll
      for (int mt = 0; mt < 4; ++mt) {
        half8 vf = *(const half8*)(sb + 8192 + (16 * mt + l15) * 128 +
                                   ((g * 16 + kk * 64) ^ swz));
        oacc[mt] = __builtin_amdgcn_mfma_f32_16x16x32_f16(vf, pf, oacc[mt], 0, 0, 0);
      }
    }
    __builtin_amdgcn_s_setprio(0);
    cur = cur + 1 >= 3 ? 0 : cur + 1;
  }
  #undef FL_STAGE

  const float inv = 1.0f / lsum;
  _Float16* op = ao + (size_t)(qrow0 + wv * 16 + l15) * 512 + h * DH;
  #pragma unroll
  for (int mt = 0; mt < 4; ++mt) {
    half4v hv;
    hv[0] = (_Float16)(oacc[mt][0] * inv);
    hv[1] = (_Float16)(oacc[mt][1] * inv);
    hv[2] = (_Float16)(oacc[mt][2] * inv);
    hv[3] = (_Float16)(oacc[mt][3] * inv);
    *(half4v*)(op + 16 * mt + 4 * g) = hv;
  }
}

extern "C" void kernel_launch(void* const* d_in, const int* in_sizes, int n_in,
                              void* d_out, int out_size, void* d_ws, size_t ws_size,
                              hipStream_t stream) {
  const float* x     = (const float*)d_in[0];
  const float* gamma = (const float*)d_in[1];
  const float* beta  = (const float*)d_in[2];
  const float* W_qk  = (const float*)d_in[3];
  const float* W_v   = (const float*)d_in[4];
  const float* W_out = (const float*)d_in[5];
  float* out = (float*)d_out;
  char* ws = (char*)d_ws;

  const size_t MB = 1024 * 1024;
  _Float16* xn16  = (_Float16*)ws;                    //  8 MiB [8192,512]
  _Float16* qkh   = (_Float16*)(ws + 8 * MB);         // 16 MiB [8192,1024]
  _Float16* vt    = (_Float16*)(ws + 24 * MB);        //  8 MiB per-head V^T
  _Float16* ao16  = (_Float16*)(ws + 32 * MB);        //  8 MiB [8192,512]
  _Float16* WqkvT = (_Float16*)(ws + 40 * MB);        // 1.5 MiB [1536,512]
  _Float16* WoutT = (_Float16*)(ws + 42 * MB);        // 0.5 MiB [512,512]

  transpose_cvt3_kernel<<<dim3(32, 16, 3), 256, 0, stream>>>(
      W_qk, W_v, W_out, WqkvT, WoutT);
  ln_kernel<<<TOK / 4, 256, 0, stream>>>(x, gamma, beta, xn16);
  hgemm_kernel<3><<<dim3(64, 12), 256, 0, stream>>>(
      xn16, WqkvT, qkh, vt, TOK, 1536, 512);
  flash16_kernel<<<dim3(64, 8), 512, 0, stream>>>(qkh, vt, ao16);
  hgemm_kernel<0><<<dim3(64, 4), 256, 0, stream>>>(
      ao16, WoutT, out, nullptr, TOK, 512, 512);
}

// Round 7
// 74.448 us; speedup vs baseline: 9.5429x; 1.1001x over previous
//
#include <hip/hip_runtime.h>

#define TOK 8192       // B*N rows
#define DMODEL 512
#define SEQ 1024
#define NH 8
#define DH 64

typedef _Float16 half8 __attribute__((ext_vector_type(8)));
typedef _Float16 half4v __attribute__((ext_vector_type(4)));
typedef float floatx4 __attribute__((ext_vector_type(4)));

__device__ __forceinline__ void gll16(const void* g, void* l) {
  __builtin_amdgcn_global_load_lds(
      (const __attribute__((address_space(1))) void*)g,
      (__attribute__((address_space(3))) void*)l, 16, 0, 0);
}

// ------- prep: LayerNorm (blocks 0..2047) + 3 weight transposes (2048..3583)
__global__ __launch_bounds__(256) void prep_kernel(
    const float* __restrict__ x, const float* __restrict__ gamma,
    const float* __restrict__ beta, _Float16* __restrict__ xn,
    const float* __restrict__ Wqk, const float* __restrict__ Wv,
    const float* __restrict__ Wo, _Float16* __restrict__ WqkvT,
    _Float16* __restrict__ WoutT) {
  __shared__ float t[32][33];
  const int bid = blockIdx.x;
  if (bid < 2048) {
    const int row = bid * 4 + (threadIdx.x >> 6);
    const int tt = threadIdx.x & 63;
    const float* xr = x + (size_t)row * DMODEL;
    const float4 a = *(const float4*)(xr + tt * 4);
    const float4 b = *(const float4*)(xr + 256 + tt * 4);
    float s  = a.x + a.y + a.z + a.w + b.x + b.y + b.z + b.w;
    float ss = a.x*a.x + a.y*a.y + a.z*a.z + a.w*a.w
             + b.x*b.x + b.y*b.y + b.z*b.z + b.w*b.w;
    #pragma unroll
    for (int m = 1; m < 64; m <<= 1) {
      s  += __shfl_xor(s, m);
      ss += __shfl_xor(ss, m);
    }
    const float mean = s * (1.0f / DMODEL);
    const float var  = ss * (1.0f / DMODEL) - mean * mean;
    const float inv  = rsqrtf(var + 1e-5f);
    const float4 g0  = *(const float4*)(gamma + tt * 4);
    const float4 g1  = *(const float4*)(gamma + 256 + tt * 4);
    const float4 be0 = *(const float4*)(beta + tt * 4);
    const float4 be1 = *(const float4*)(beta + 256 + tt * 4);
    half4v o0, o1;
    o0[0] = (_Float16)((a.x - mean) * inv * g0.x + be0.x);
    o0[1] = (_Float16)((a.y - mean) * inv * g0.y + be0.y);
    o0[2] = (_Float16)((a.z - mean) * inv * g0.z + be0.z);
    o0[3] = (_Float16)((a.w - mean) * inv * g0.w + be0.w);
    o1[0] = (_Float16)((b.x - mean) * inv * g1.x + be1.x);
    o1[1] = (_Float16)((b.y - mean) * inv * g1.y + be1.y);
    o1[2] = (_Float16)((b.z - mean) * inv * g1.z + be1.z);
    o1[3] = (_Float16)((b.w - mean) * inv * g1.w + be1.w);
    _Float16* outr = xn + (size_t)row * DMODEL;
    *(half4v*)(outr + tt * 4) = o0;
    *(half4v*)(outr + 256 + tt * 4) = o1;
  } else {
    const int r = bid - 2048;          // 0..1535
    const int z = r >> 9;              // 0,1,2
    const int rem = r & 511;
    const float* W;
    _Float16* dst;
    int N, rowoff;
    if (z == 0)      { W = Wqk; dst = WqkvT; N = 1024; rowoff = 0; }
    else if (z == 1) { W = Wv;  dst = WqkvT; N = 512;  rowoff = 1024; }
    else             { W = Wo;  dst = WoutT; N = 512;  rowoff = 0; }
    const int n0 = (rem & 31) * 32;
    if (n0 >= N) return;
    const int k0 = (rem >> 5) * 32;
    const int tx = threadIdx.x & 31, ty = threadIdx.x >> 5;
    #pragma unroll
    for (int j = 0; j < 4; ++j)
      t[ty + j * 8][tx] = W[(size_t)(k0 + ty + j * 8) * N + n0 + tx];
    __syncthreads();
    #pragma unroll
    for (int j = 0; j < 4; ++j)
      dst[(size_t)(rowoff + n0 + ty + j * 8) * 512 + k0 + tx] =
          (_Float16)t[tx][ty + j * 8];
  }
}

// ---------------- f16 MFMA GEMM: C = A[M,K] * Bt[N,K]^T ----------------
// BK=32, NBUF=3, prefetch distance 2, counted vmcnt + raw s_barrier.
// 64B rows in LDS, swizzle: chunk ^= ((row>>1)&3)<<4 (2-way max conflicts).
// MODE 0: fp32 C[M,512]
// MODE 3: fused QKV epilogue: n<1024 -> qkh[M,1024]; n>=1024 -> vt transposed
template <int MODE>
__global__ __launch_bounds__(256) void hgemm_kernel(
    const _Float16* __restrict__ A, const _Float16* __restrict__ Bt,
    void* __restrict__ Cout, void* __restrict__ Cout2, int M, int N, int K) {
  __shared__ char smem[49152];  // 3 x (A 8K | B 8K)
  const int tid = threadIdx.x;
  const int bm = blockIdx.x, bn = blockIdx.y;
  const int wv = tid >> 6, lane = tid & 63;
  const int l15 = lane & 15, g = lane >> 4;
  const int wr = wv >> 1, wc = wv & 1;
  const int rswz = ((l15 >> 1) & 3) << 4;       // fragment-read swizzle
  const _Float16* Ab = A + (size_t)(bm * 128) * K;
  const _Float16* Bb = Bt + (size_t)(bn * 128) * K;
  const int lrow = lane >> 2;                   // 0..15
  const int lchk = (lane & 3) * 16;             // byte chunk in 64B row
  const int ssw = lchk ^ (((lrow >> 1) & 3) << 4);  // pre-swizzled src offset

  // stage: A rows [wv*16 + i*64, +16), 64B/row; LDS dest wave-uniform base
  #define HG_STAGE(buf, kt)                                                   \
    _Pragma("unroll")                                                         \
    for (int i = 0; i < 2; ++i) {                                             \
      const int rbase = wv * 16 + i * 64;                                     \
      gll16((const char*)(Ab + (size_t)(rbase + lrow) * K + (kt)) + ssw,      \
            smem + (buf) * 16384 + rbase * 64);                               \
      gll16((const char*)(Bb + (size_t)(rbase + lrow) * K + (kt)) + ssw,      \
            smem + (buf) * 16384 + 8192 + rbase * 64);                        \
    }

  floatx4 acc[4][4] = {};
  HG_STAGE(0, 0);
  HG_STAGE(1, 32);
  int cur = 0;
  const int nit = K >> 5;           // 16 for K=512
  for (int it = 0; it < nit; ++it) {
    if (it < nit - 2) asm volatile("s_waitcnt vmcnt(4)" ::: "memory");
    else              asm volatile("s_waitcnt vmcnt(0)" ::: "memory");
    __builtin_amdgcn_s_barrier();
    asm volatile("" ::: "memory");
    const int nxt = cur + 2 >= 3 ? cur - 1 : cur + 2;
    if (it + 2 < nit) { HG_STAGE(nxt, (it + 2) * 32); }
    const char* sb = smem + cur * 16384;
    half8 af[4], bf[4];
    #pragma unroll
    for (int mt = 0; mt < 4; ++mt)
      af[mt] = *(const half8*)(sb + (wr * 64 + mt * 16 + l15) * 64 +
                               (g * 16 ^ rswz));
    #pragma unroll
    for (int nt = 0; nt < 4; ++nt)
      bf[nt] = *(const half8*)(sb + 8192 + (wc * 64 + nt * 16 + l15) * 64 +
                               (g * 16 ^ rswz));
    __builtin_amdgcn_s_setprio(1);
    #pragma unroll
    for (int mt = 0; mt < 4; ++mt)
      #pragma unroll
      for (int nt = 0; nt < 4; ++nt)
        acc[mt][nt] = __builtin_amdgcn_mfma_f32_16x16x32_f16(
            af[mt], bf[nt], acc[mt][nt], 0, 0, 0);
    __builtin_amdgcn_s_setprio(0);
    cur = cur + 1 >= 3 ? 0 : cur + 1;
  }
  #undef HG_STAGE
  const int m0 = bm * 128 + wr * 64;
  const int n0 = bn * 128 + wc * 64;
  if constexpr (MODE == 0) {
    float* C = (float*)Cout;
    #pragma unroll
    for (int mt = 0; mt < 4; ++mt)
      #pragma unroll
      for (int nt = 0; nt < 4; ++nt) {
        const int n = n0 + nt * 16 + l15;
        #pragma unroll
        for (int r = 0; r < 4; ++r)
          C[(size_t)(m0 + mt * 16 + 4 * g + r) * 512 + n] = acc[mt][nt][r];
      }
  } else {
    _Float16* Q = (_Float16*)Cout;   // qkh [M,1024]
    _Float16* V = (_Float16*)Cout2;  // vt  per-head transposed
    #pragma unroll
    for (int mt = 0; mt < 4; ++mt) {
      const int mrow = m0 + mt * 16 + 4 * g;
      const int b = mrow >> 10, tok = mrow & 1023;
      #pragma unroll
      for (int nt = 0; nt < 4; ++nt) {
        const int n = n0 + nt * 16 + l15;   // uniform side per (bn,wc,nt)
        if (n < 1024) {
          #pragma unroll
          for (int r = 0; r < 4; ++r)
            Q[(size_t)(mrow + r) * 1024 + n] = (_Float16)acc[mt][nt][r];
        } else {
          const int cv = n - 1024;
          half4v hv;
          #pragma unroll
          for (int r = 0; r < 4; ++r) hv[r] = (_Float16)acc[mt][nt][r];
          *(half4v*)(V + ((size_t)((b * 8 + (cv >> 6)) * 64 + (cv & 63)) << 10) + tok) = hv;
        }
      }
    }
  }
}

// ---------------- flash attention, fp16 MFMA, fixed-offset softmax ----------
// NBUF=3 pipeline, counted vmcnt + raw s_barrier (prefetch distance 2).
// blockIdx.x = bh (XCD-local KV). qkh: [8192,1024]; vt per-head T; ao f16.
#define QSC 0.18033688f   // 0.125 * log2(e)
#define MOFF 5.7707801f   // 4 * log2(e)

__global__ __launch_bounds__(512) void flash16_kernel(
    const _Float16* __restrict__ qkh, const _Float16* __restrict__ vt,
    _Float16* __restrict__ ao) {
  __shared__ char smem[65536];   // 3 x (K 8K | V 8K) | P 8x2K @49152
  const int bh = blockIdx.x;     // 0..63
  const int qt = blockIdx.y;     // 0..7
  const int b = bh >> 3, h = bh & 7;
  const int tid = threadIdx.x;
  const int wv = tid >> 6, lane = tid & 63;
  const int l15 = lane & 15, g = lane >> 4;
  const int swz = (l15 & 7) << 4;
  const int qrow0 = b * SEQ + qt * 128;

  half8 qf[2];
  {
    const _Float16* qp = qkh + (size_t)(qrow0 + wv * 16 + l15) * 1024 + h * DH;
    qf[0] = *(const half8*)(qp + g * 8);
    qf[1] = *(const half8*)(qp + g * 8 + 32);
    qf[0] *= (_Float16)QSC;
    qf[1] *= (_Float16)QSC;
  }

  float lsum = 0.f;
  floatx4 oacc[4] = {};

  const int lrow = lane >> 3;
  const int lchk = (lane & 7) * 16;
  const int ssw = lchk ^ (lrow << 4);
  const _Float16* kbase = qkh + 512 + h * DH;
  const _Float16* vbase = vt + (size_t)bh * 64 * 1024;
  char* pb = smem + 49152 + wv * 2048 + l15 * 128;   // per-wave P strip

  #define FL_STAGE(buf, kt)                                                   \
    {                                                                         \
      const int krow = b * SEQ + (kt) * 64 + wv * 8 + lrow;                   \
      gll16((const char*)(kbase + (size_t)krow * 1024) + ssw,                 \
            smem + (buf) * 16384 + wv * 1024);                                \
      gll16((const char*)(vbase + (size_t)(wv * 8 + lrow) * 1024 +            \
                          (kt) * 64) + ssw,                                   \
            smem + (buf) * 16384 + 8192 + wv * 1024);                         \
    }

  FL_STAGE(0, 0);
  FL_STAGE(1, 1);
  int cur = 0;
  for (int kt = 0; kt < 16; ++kt) {
    if (kt < 15) asm volatile("s_waitcnt vmcnt(2)" ::: "memory");
    else         asm volatile("s_waitcnt vmcnt(0)" ::: "memory");
    __builtin_amdgcn_s_barrier();
    asm volatile("" ::: "memory");
    const int nxt = cur + 2 >= 3 ? cur - 1 : cur + 2;
    if (kt + 2 < 16) FL_STAGE(nxt, kt + 2);
    const char* sb = smem + cur * 16384;

    // S2^T[k][q] = mfma(A=K, B=Qscaled)
    floatx4 sacc[4] = {};
    __builtin_amdgcn_s_setprio(1);
    #pragma unroll
    for (int kk = 0; kk < 2; ++kk) {
      #pragma unroll
      for (int mt = 0; mt < 4; ++mt) {
        half8 af = *(const half8*)(sb + (16 * mt + l15) * 128 +
                                   ((g * 16 + kk * 64) ^ swz));
        sacc[mt] = __builtin_amdgcn_mfma_f32_16x16x32_f16(af, qf[kk], sacc[mt], 0, 0, 0);
      }
    }
    __builtin_amdgcn_s_setprio(0);

    // fixed-offset softmax: p = 2^(s2 - MOFF); 1/lsum cancels the offset
    float rs = 0.f;
    #pragma unroll
    for (int mt = 0; mt < 4; ++mt) {
      float p0 = exp2f(sacc[mt][0] - MOFF);
      float p1 = exp2f(sacc[mt][1] - MOFF);
      float p2 = exp2f(sacc[mt][2] - MOFF);
      float p3 = exp2f(sacc[mt][3] - MOFF);
      rs += (p0 + p1) + (p2 + p3);
      half4v pv;
      pv[0] = (_Float16)p0; pv[1] = (_Float16)p1;
      pv[2] = (_Float16)p2; pv[3] = (_Float16)p3;
      *(half4v*)(pb + ((32 * mt + 8 * g) ^ swz)) = pv;
    }
    rs += __shfl_xor(rs, 16);
    rs += __shfl_xor(rs, 32);
    lsum += rs;

    // O^T[d][q] += mfma(A=Vt, B=P^T)
    __builtin_amdgcn_s_setprio(1);
    #pragma unroll
    for (int kk = 0; kk < 2; ++kk) {
      half8 pf = *(const half8*)(pb + ((g * 16 + kk * 64) ^ swz));
      #pragma unroll
      for (int mt = 0; mt < 4; ++mt) {
        half8 vf = *(const half8*)(sb + 8192 + (16 * mt + l15) * 128 +
                                   ((g * 16 + kk * 64) ^ swz));
        oacc[mt] = __builtin_amdgcn_mfma_f32_16x16x32_f16(vf, pf, oacc[mt], 0, 0, 0);
      }
    }
    __builtin_amdgcn_s_setprio(0);
    cur = cur + 1 >= 3 ? 0 : cur + 1;
  }
  #undef FL_STAGE

  const float inv = 1.0f / lsum;
  _Float16* op = ao + (size_t)(qrow0 + wv * 16 + l15) * 512 + h * DH;
  #pragma unroll
  for (int mt = 0; mt < 4; ++mt) {
    half4v hv;
    hv[0] = (_Float16)(oacc[mt][0] * inv);
    hv[1] = (_Float16)(oacc[mt][1] * inv);
    hv[2] = (_Float16)(oacc[mt][2] * inv);
    hv[3] = (_Float16)(oacc[mt][3] * inv);
    *(half4v*)(op + 16 * mt + 4 * g) = hv;
  }
}

extern "C" void kernel_launch(void* const* d_in, const int* in_sizes, int n_in,
                              void* d_out, int out_size, void* d_ws, size_t ws_size,
                              hipStream_t stream) {
  const float* x     = (const float*)d_in[0];
  const float* gamma = (const float*)d_in[1];
  const float* beta  = (const float*)d_in[2];
  const float* W_qk  = (const float*)d_in[3];
  const float* W_v   = (const float*)d_in[4];
  const float* W_out = (const float*)d_in[5];
  float* out = (float*)d_out;
  char* ws = (char*)d_ws;

  const size_t MB = 1024 * 1024;
  _Float16* xn16  = (_Float16*)ws;                    //  8 MiB [8192,512]
  _Float16* qkh   = (_Float16*)(ws + 8 * MB);         // 16 MiB [8192,1024]
  _Float16* vt    = (_Float16*)(ws + 24 * MB);        //  8 MiB per-head V^T
  _Float16* ao16  = (_Float16*)(ws + 32 * MB);        //  8 MiB [8192,512]
  _Float16* WqkvT = (_Float16*)(ws + 40 * MB);        // 1.5 MiB [1536,512]
  _Float16* WoutT = (_Float16*)(ws + 42 * MB);        // 0.5 MiB [512,512]

  prep_kernel<<<3584, 256, 0, stream>>>(x, gamma, beta, xn16,
                                        W_qk, W_v, W_out, WqkvT, WoutT);
  hgemm_kernel<3><<<dim3(64, 12), 256, 0, stream>>>(
      xn16, WqkvT, qkh, vt, TOK, 1536, 512);
  flash16_kernel<<<dim3(64, 8), 512, 0, stream>>>(qkh, vt, ao16);
  hgemm_kernel<0><<<dim3(64, 4), 256, 0, stream>>>(
      ao16, WoutT, out, nullptr, TOK, 512, 512);
}